// Round 1
// baseline (456.701 us; speedup 1.0000x reference)
//
#include <hip/hip_runtime.h>
#include <math.h>

#define N_NODES 100000
#define N_EDGES 1000000
#define N_GRAPHS 1024
#define BN_EPS 1e-5f

// ---------- helpers ----------
static __device__ __forceinline__ float elu_f(float v) {
    return v > 0.f ? v : expm1f(v);
}

// monotone float -> uint mapping (order-preserving) for atomicMax on floats
static __device__ __forceinline__ unsigned fmap(float f) {
    unsigned u = __float_as_uint(f);
    return (u & 0x80000000u) ? ~u : (u | 0x80000000u);
}
static __device__ __forceinline__ float funmap(unsigned u) {
    unsigned b = (u & 0x80000000u) ? (u & 0x7FFFFFFFu) : ~u;
    return __uint_as_float(b);
}
#define NEG_INF_MAPPED 0x007FFFFFu  // fmap(-inf)

// ---------- prep: fold BN, compute Wq = Wp - Wt, combined biases ----------
__global__ void prep_kernel(const float* __restrict__ Wt1, const float* __restrict__ bt1,
                            const float* __restrict__ Wp1, const float* __restrict__ bp1,
                            const float* __restrict__ gamma, const float* __restrict__ beta,
                            const float* __restrict__ mean,  const float* __restrict__ var,
                            const float* __restrict__ Wt2, const float* __restrict__ bt2,
                            const float* __restrict__ Wp2, const float* __restrict__ bp2,
                            const float* __restrict__ Wt3, const float* __restrict__ bt3,
                            const float* __restrict__ Wp3, const float* __restrict__ bp3,
                            float* __restrict__ Wt1e, float* __restrict__ Wq1, float* __restrict__ qb1,
                            float* __restrict__ Wq2,  float* __restrict__ qb2,
                            float* __restrict__ Wq3,  float* __restrict__ qb3) {
    int i = blockIdx.x * blockDim.x + threadIdx.x;
    if (i < 32 * 128) {
        int c = i / 128;
        float s = gamma[c] * rsqrtf(var[c] + BN_EPS);
        Wt1e[i] = Wt1[i] * s;
        Wq1[i] = (Wp1[i] - Wt1[i]) * s;
    }
    if (i < 32) {
        float s = gamma[i] * rsqrtf(var[i] + BN_EPS);
        qb1[i] = (bt1[i] + bp1[i]) * s + beta[i] - mean[i] * s;
    }
    if (i < 64 * 32) Wq2[i] = Wp2[i] - Wt2[i];
    if (i < 64) qb2[i] = bt2[i] + bp2[i];
    if (i < 64 * 64) Wq3[i] = Wp3[i] - Wt3[i];
    if (i < 64) qb3[i] = bt3[i] + bp3[i];
}

// ---------- CSR build ----------
__global__ void zero2_kernel(int* __restrict__ a, int* __restrict__ b, int n) {
    int i = blockIdx.x * blockDim.x + threadIdx.x;
    if (i < n) { a[i] = 0; b[i] = 0; }
}

__global__ void count_kernel(const int* __restrict__ dst, int* __restrict__ counts, int E) {
    int i = blockIdx.x * blockDim.x + threadIdx.x;
    if (i < E) atomicAdd(&counts[dst[i]], 1);
}

// 3-phase exclusive scan over counts[n] -> offsets[n+1]
#define SCAN_ELEMS 1024
__global__ void scan_sum_kernel(const int* __restrict__ counts, int* __restrict__ bsums, int n) {
    int tid = threadIdx.x;
    int base = blockIdx.x * SCAN_ELEMS + tid * 4;
    int s = 0;
#pragma unroll
    for (int j = 0; j < 4; j++) { int i = base + j; if (i < n) s += counts[i]; }
    __shared__ int red[256];
    red[tid] = s; __syncthreads();
    for (int off = 128; off > 0; off >>= 1) {
        if (tid < off) red[tid] += red[tid + off];
        __syncthreads();
    }
    if (tid == 0) bsums[blockIdx.x] = red[0];
}

__global__ void scan_top_kernel(int* __restrict__ bsums, int nb, int* __restrict__ offsets, int n) {
    if (blockIdx.x == 0 && threadIdx.x == 0) {
        int run = 0;
        for (int b = 0; b < nb; b++) { int t = bsums[b]; bsums[b] = run; run += t; }
        offsets[n] = run;
    }
}

__global__ void scan_out_kernel(const int* __restrict__ counts, const int* __restrict__ bsums,
                                int* __restrict__ offsets, int n) {
    int tid = threadIdx.x;
    int base = blockIdx.x * SCAN_ELEMS + tid * 4;
    int v[4]; int tsum = 0;
#pragma unroll
    for (int j = 0; j < 4; j++) { int i = base + j; v[j] = (i < n) ? counts[i] : 0; tsum += v[j]; }
    __shared__ int sc[256];
    sc[tid] = tsum; __syncthreads();
    for (int off = 1; off < 256; off <<= 1) {
        int u = (tid >= off) ? sc[tid - off] : 0;
        __syncthreads();
        sc[tid] += u;
        __syncthreads();
    }
    int run = sc[tid] - tsum + bsums[blockIdx.x];  // exclusive prefix for this thread
#pragma unroll
    for (int j = 0; j < 4; j++) {
        int i = base + j;
        if (i < n) offsets[i] = run;
        run += v[j];
    }
}

__global__ void fill_kernel(const int* __restrict__ src, const int* __restrict__ dst,
                            const int* __restrict__ offsets, int* __restrict__ cursor,
                            int* __restrict__ csr, int E) {
    int i = blockIdx.x * blockDim.x + threadIdx.x;
    if (i < E) {
        int d = dst[i];
        int pos = atomicAdd(&cursor[d], 1);
        csr[offsets[d] + pos] = src[i];
    }
}

// ---------- per-node transform: t = x@WtE^T ; q = x@Wq^T + qbias ----------
// F = f_out per matrix; thread layout: tx in [0,F) = channel, ty = node row.
// Each thread computes NN nodes x {t,q} for one channel.
template <int F_IN, int F>
__global__ __launch_bounds__(256) void transform_kernel(
        const float* __restrict__ x, const float* __restrict__ Wt,
        const float* __restrict__ Wq, const float* __restrict__ qbias,
        float* __restrict__ t, float* __restrict__ q) {
    constexpr int NT = 256 / F;     // node rows of threads
    constexpr int NN = 4;           // nodes per thread
    constexpr int NPB = NT * NN;    // nodes per block

    __shared__ float xs[NPB][F_IN];
    __shared__ float ws[F_IN][2 * F + 1];  // transposed, padded: [k][c]

    int tid = threadIdx.x;

    // load x tile (contiguous nodes) as float4
    const float* xblk = x + (size_t)blockIdx.x * NPB * F_IN;
    for (int idx = tid * 4; idx < NPB * F_IN; idx += 256 * 4) {
        float4 v = *reinterpret_cast<const float4*>(xblk + idx);
        *reinterpret_cast<float4*>(&xs[0][0] + idx) = v;
    }
    // load weights transposed into LDS
    for (int idx = tid; idx < F * F_IN; idx += 256) {
        int c = idx / F_IN, k = idx % F_IN;
        ws[k][c] = Wt[idx];
        ws[k][c + F] = Wq[idx];
    }
    __syncthreads();

    int tx = tid % F;
    int ty = tid / F;
    int nb = ty * NN;

    float acc[NN][2];
#pragma unroll
    for (int i = 0; i < NN; i++) { acc[i][0] = 0.f; acc[i][1] = 0.f; }

#pragma unroll 4
    for (int k = 0; k < F_IN; k++) {
        float wt = ws[k][tx];
        float wq = ws[k][tx + F];
#pragma unroll
        for (int i = 0; i < NN; i++) {
            float xv = xs[nb + i][k];
            acc[i][0] = fmaf(xv, wt, acc[i][0]);
            acc[i][1] = fmaf(xv, wq, acc[i][1]);
        }
    }

    float qb = qbias[tx];
#pragma unroll
    for (int i = 0; i < NN; i++) {
        size_t node = (size_t)blockIdx.x * NPB + nb + i;
        t[node * F + tx] = acc[i][0];
        q[node * F + tx] = acc[i][1] + qb;
    }
}

// ---------- edge max + combine + ELU ----------
// out[d][c] = indeg(d)>0 ? elu(t[d][c] + max_{s in in(d)} q[s][c]) : 0
template <int F>
__global__ __launch_bounds__(256) void edgemax_kernel(
        const float* __restrict__ t, const float* __restrict__ q,
        const int* __restrict__ offsets, const int* __restrict__ csr,
        float* __restrict__ out, int N) {
    constexpr int G = 256 / F;
    int g = threadIdx.x / F;
    int c = threadIdx.x % F;
    int nd = blockIdx.x * G + g;
    if (nd >= N) return;
    int beg = offsets[nd], end = offsets[nd + 1];
    float m = -INFINITY;
    for (int i = beg; i < end; i++) {
        int s = csr[i];
        m = fmaxf(m, q[(size_t)s * F + c]);
    }
    float r;
    if (beg < end) {
        float v = t[(size_t)nd * F + c] + m;
        r = elu_f(v);
    } else {
        r = 0.f;
    }
    out[(size_t)nd * F + c] = r;
}

// ---------- graph max pooling ----------
__global__ void pool_init_kernel(unsigned* __restrict__ p, int n) {
    int i = blockIdx.x * blockDim.x + threadIdx.x;
    if (i < n) p[i] = NEG_INF_MAPPED;
}

__global__ void pool_kernel(const float* __restrict__ x, const int* __restrict__ gid,
                            unsigned* __restrict__ pooled, int N) {
    const int CHUNK = 128;
    int wave = (blockIdx.x * blockDim.x + threadIdx.x) >> 6;
    int lane = threadIdx.x & 63;
    int start = wave * CHUNK;
    if (start >= N) return;
    int end = min(start + CHUNK, N);
    float m = -INFINITY;
    int cur = gid[start];
    for (int n = start; n < end; n++) {
        int g = gid[n];
        if (g != cur) {
            atomicMax(&pooled[cur * 64 + lane], fmap(m));
            cur = g;
            m = -INFINITY;
        }
        m = fmaxf(m, x[(size_t)n * 64 + lane]);
    }
    atomicMax(&pooled[cur * 64 + lane], fmap(m));
}

// ---------- FC head + log_softmax, one block (64 threads) per graph ----------
__global__ __launch_bounds__(64) void fc_kernel(
        const unsigned* __restrict__ pooled,
        const float* __restrict__ Wf1, const float* __restrict__ bf1,
        const float* __restrict__ Wf2, const float* __restrict__ bf2,
        const float* __restrict__ Wf3, const float* __restrict__ bf3,
        float* __restrict__ out) {
    int g = blockIdx.x;
    int c = threadIdx.x;
    __shared__ float x0[64], h1[64], h2[32], h3[10];

    unsigned u = pooled[g * 64 + c];
    x0[c] = (u == NEG_INF_MAPPED) ? 0.f : funmap(u);
    __syncthreads();

    float a = bf1[c];
#pragma unroll 8
    for (int k = 0; k < 64; k++) a = fmaf(Wf1[c * 64 + k], x0[k], a);
    h1[c] = elu_f(a);
    __syncthreads();

    if (c < 32) {
        float a2 = bf2[c];
#pragma unroll 8
        for (int k = 0; k < 64; k++) a2 = fmaf(Wf2[c * 64 + k], h1[k], a2);
        h2[c] = elu_f(a2);
    }
    __syncthreads();

    if (c < 10) {
        float a3 = bf3[c];
#pragma unroll 8
        for (int k = 0; k < 32; k++) a3 = fmaf(Wf3[c * 32 + k], h2[k], a3);
        h3[c] = a3;
    }
    __syncthreads();

    if (c < 10) {
        float mx = h3[0];
#pragma unroll
        for (int j = 1; j < 10; j++) mx = fmaxf(mx, h3[j]);
        float s = 0.f;
#pragma unroll
        for (int j = 0; j < 10; j++) s += expf(h3[j] - mx);
        out[g * 10 + c] = h3[c] - mx - logf(s);
    }
}

// ---------- launch ----------
extern "C" void kernel_launch(void* const* d_in, const int* in_sizes, int n_in,
                              void* d_out, int out_size, void* d_ws, size_t ws_size,
                              hipStream_t stream) {
    const float* atom = (const float*)d_in[0];
    const int* esrc = (const int*)d_in[1];
    const int* edst = (const int*)d_in[2];
    const int* gid  = (const int*)d_in[3];
    const float* Wt1 = (const float*)d_in[4];
    const float* bt1 = (const float*)d_in[5];
    const float* Wp1 = (const float*)d_in[6];
    const float* bp1 = (const float*)d_in[7];
    const float* bng = (const float*)d_in[8];
    const float* bnb = (const float*)d_in[9];
    const float* bnm = (const float*)d_in[10];
    const float* bnv = (const float*)d_in[11];
    const float* Wt2 = (const float*)d_in[12];
    const float* bt2 = (const float*)d_in[13];
    const float* Wp2 = (const float*)d_in[14];
    const float* bp2 = (const float*)d_in[15];
    const float* Wt3 = (const float*)d_in[16];
    const float* bt3 = (const float*)d_in[17];
    const float* Wp3 = (const float*)d_in[18];
    const float* bp3 = (const float*)d_in[19];
    const float* Wf1 = (const float*)d_in[20];
    const float* bf1 = (const float*)d_in[21];
    const float* Wf2 = (const float*)d_in[22];
    const float* bf2 = (const float*)d_in[23];
    const float* Wf3 = (const float*)d_in[24];
    const float* bf3 = (const float*)d_in[25];

    // workspace carve-up
    char* p = (char*)d_ws;
    auto alloc = [&](size_t bytes) -> void* {
        void* r = (void*)p;
        p += (bytes + 255) & ~(size_t)255;
        return r;
    };
    int* offsets = (int*)alloc(sizeof(int) * (N_NODES + 1));
    int* counts  = (int*)alloc(sizeof(int) * N_NODES);
    int* cursor  = (int*)alloc(sizeof(int) * N_NODES);
    int* bsums   = (int*)alloc(sizeof(int) * 128);
    int* csr     = (int*)alloc(sizeof(int) * N_EDGES);
    float* Wt1e  = (float*)alloc(sizeof(float) * 32 * 128);
    float* Wq1   = (float*)alloc(sizeof(float) * 32 * 128);
    float* qb1   = (float*)alloc(sizeof(float) * 32);
    float* Wq2   = (float*)alloc(sizeof(float) * 64 * 32);
    float* qb2   = (float*)alloc(sizeof(float) * 64);
    float* Wq3   = (float*)alloc(sizeof(float) * 64 * 64);
    float* qb3   = (float*)alloc(sizeof(float) * 64);
    float* tbuf  = (float*)alloc(sizeof(float) * (size_t)N_NODES * 64);
    float* qbuf  = (float*)alloc(sizeof(float) * (size_t)N_NODES * 64);
    float* xbuf  = (float*)alloc(sizeof(float) * (size_t)N_NODES * 64);
    unsigned* pooled = (unsigned*)alloc(sizeof(unsigned) * N_GRAPHS * 64);

    const int NB_SCAN = (N_NODES + SCAN_ELEMS - 1) / SCAN_ELEMS;  // 98

    // prep + CSR build
    zero2_kernel<<<(N_NODES + 255) / 256, 256, 0, stream>>>(counts, cursor, N_NODES);
    prep_kernel<<<16, 256, 0, stream>>>(Wt1, bt1, Wp1, bp1, bng, bnb, bnm, bnv,
                                        Wt2, bt2, Wp2, bp2, Wt3, bt3, Wp3, bp3,
                                        Wt1e, Wq1, qb1, Wq2, qb2, Wq3, qb3);
    count_kernel<<<(N_EDGES + 255) / 256, 256, 0, stream>>>(edst, counts, N_EDGES);
    scan_sum_kernel<<<NB_SCAN, 256, 0, stream>>>(counts, bsums, N_NODES);
    scan_top_kernel<<<1, 64, 0, stream>>>(bsums, NB_SCAN, offsets, N_NODES);
    scan_out_kernel<<<NB_SCAN, 256, 0, stream>>>(counts, bsums, offsets, N_NODES);
    fill_kernel<<<(N_EDGES + 255) / 256, 256, 0, stream>>>(esrc, edst, offsets, cursor, csr, N_EDGES);

    // layer 1: 128 -> 32 (BN folded)
    transform_kernel<128, 32><<<N_NODES / 32, 256, 0, stream>>>(atom, Wt1e, Wq1, qb1, tbuf, qbuf);
    edgemax_kernel<32><<<N_NODES / 8, 256, 0, stream>>>(tbuf, qbuf, offsets, csr, xbuf, N_NODES);

    // layer 2: 32 -> 64
    transform_kernel<32, 64><<<N_NODES / 16, 256, 0, stream>>>(xbuf, Wt2, Wq2, qb2, tbuf, qbuf);
    edgemax_kernel<64><<<N_NODES / 4, 256, 0, stream>>>(tbuf, qbuf, offsets, csr, xbuf, N_NODES);

    // layer 3: 64 -> 64
    transform_kernel<64, 64><<<N_NODES / 16, 256, 0, stream>>>(xbuf, Wt3, Wq3, qb3, tbuf, qbuf);
    edgemax_kernel<64><<<N_NODES / 4, 256, 0, stream>>>(tbuf, qbuf, offsets, csr, xbuf, N_NODES);

    // graph pooling
    pool_init_kernel<<<(N_GRAPHS * 64 + 255) / 256, 256, 0, stream>>>(pooled, N_GRAPHS * 64);
    {
        int waves = (N_NODES + 127) / 128;
        int blocks = (waves + 3) / 4;  // 4 waves per 256-thread block
        pool_kernel<<<blocks, 256, 0, stream>>>(xbuf, gid, pooled, N_NODES);
    }

    // FC head
    fc_kernel<<<N_GRAPHS, 64, 0, stream>>>(pooled, Wf1, bf1, Wf2, bf2, Wf3, bf3, (float*)d_out);
}

// Round 2
// 376.221 us; speedup vs baseline: 1.2139x; 1.2139x over previous
//
#include <hip/hip_runtime.h>
#include <hip/hip_fp16.h>
#include <math.h>

#define N_NODES 100000
#define N_EDGES 1000000
#define N_GRAPHS 1024
#define BN_EPS 1e-5f

// ---------- helpers ----------
static __device__ __forceinline__ float elu_f(float v) {
    return v > 0.f ? v : expm1f(v);
}

// packed fp16 max (2 halves) — gfx950 v_pk_max_f16
static __device__ __forceinline__ unsigned pkmax(unsigned a, unsigned b) {
    unsigned r;
    asm("v_pk_max_f16 %0, %1, %2" : "=v"(r) : "v"(a), "v"(b));
    return r;
}
#define HALF2_NEG_INF 0xFC00FC00u

// monotone float -> uint mapping (order-preserving) for atomicMax on floats
static __device__ __forceinline__ unsigned fmap(float f) {
    unsigned u = __float_as_uint(f);
    return (u & 0x80000000u) ? ~u : (u | 0x80000000u);
}
static __device__ __forceinline__ float funmap(unsigned u) {
    unsigned b = (u & 0x80000000u) ? (u & 0x7FFFFFFFu) : ~u;
    return __uint_as_float(b);
}
#define NEG_INF_MAPPED 0x007FFFFFu  // fmap(-inf)

// ---------- prep: fold BN, compute Wq = Wp - Wt, combined biases ----------
__global__ void prep_kernel(const float* __restrict__ Wt1, const float* __restrict__ bt1,
                            const float* __restrict__ Wp1, const float* __restrict__ bp1,
                            const float* __restrict__ gamma, const float* __restrict__ beta,
                            const float* __restrict__ mean,  const float* __restrict__ var,
                            const float* __restrict__ Wt2, const float* __restrict__ bt2,
                            const float* __restrict__ Wp2, const float* __restrict__ bp2,
                            const float* __restrict__ Wt3, const float* __restrict__ bt3,
                            const float* __restrict__ Wp3, const float* __restrict__ bp3,
                            float* __restrict__ Wt1e, float* __restrict__ Wq1, float* __restrict__ qb1,
                            float* __restrict__ Wq2,  float* __restrict__ qb2,
                            float* __restrict__ Wq3,  float* __restrict__ qb3) {
    int i = blockIdx.x * blockDim.x + threadIdx.x;
    if (i < 32 * 128) {
        int c = i / 128;
        float s = gamma[c] * rsqrtf(var[c] + BN_EPS);
        Wt1e[i] = Wt1[i] * s;
        Wq1[i] = (Wp1[i] - Wt1[i]) * s;
    }
    if (i < 32) {
        float s = gamma[i] * rsqrtf(var[i] + BN_EPS);
        qb1[i] = (bt1[i] + bp1[i]) * s + beta[i] - mean[i] * s;
    }
    if (i < 64 * 32) Wq2[i] = Wp2[i] - Wt2[i];
    if (i < 64) qb2[i] = bt2[i] + bp2[i];
    if (i < 64 * 64) Wq3[i] = Wp3[i] - Wt3[i];
    if (i < 64) qb3[i] = bt3[i] + bp3[i];
}

// ---------- CSR build ----------
__global__ void zero2_kernel(int* __restrict__ a, int* __restrict__ b, int n) {
    int i = blockIdx.x * blockDim.x + threadIdx.x;
    if (i < n) { a[i] = 0; b[i] = 0; }
}

__global__ void count_kernel(const int* __restrict__ dst, int* __restrict__ counts, int E) {
    int i = blockIdx.x * blockDim.x + threadIdx.x;
    if (i < E) atomicAdd(&counts[dst[i]], 1);
}

// 3-phase exclusive scan over counts[n] -> offsets[n+1]
#define SCAN_ELEMS 1024
__global__ void scan_sum_kernel(const int* __restrict__ counts, int* __restrict__ bsums, int n) {
    int tid = threadIdx.x;
    int base = blockIdx.x * SCAN_ELEMS + tid * 4;
    int s = 0;
#pragma unroll
    for (int j = 0; j < 4; j++) { int i = base + j; if (i < n) s += counts[i]; }
    __shared__ int red[256];
    red[tid] = s; __syncthreads();
    for (int off = 128; off > 0; off >>= 1) {
        if (tid < off) red[tid] += red[tid + off];
        __syncthreads();
    }
    if (tid == 0) bsums[blockIdx.x] = red[0];
}

__global__ void scan_top_kernel(int* __restrict__ bsums, int nb, int* __restrict__ offsets, int n) {
    if (blockIdx.x == 0 && threadIdx.x == 0) {
        int run = 0;
        for (int b = 0; b < nb; b++) { int t = bsums[b]; bsums[b] = run; run += t; }
        offsets[n] = run;
    }
}

__global__ void scan_out_kernel(const int* __restrict__ counts, const int* __restrict__ bsums,
                                int* __restrict__ offsets, int n) {
    int tid = threadIdx.x;
    int base = blockIdx.x * SCAN_ELEMS + tid * 4;
    int v[4]; int tsum = 0;
#pragma unroll
    for (int j = 0; j < 4; j++) { int i = base + j; v[j] = (i < n) ? counts[i] : 0; tsum += v[j]; }
    __shared__ int sc[256];
    sc[tid] = tsum; __syncthreads();
    for (int off = 1; off < 256; off <<= 1) {
        int u = (tid >= off) ? sc[tid - off] : 0;
        __syncthreads();
        sc[tid] += u;
        __syncthreads();
    }
    int run = sc[tid] - tsum + bsums[blockIdx.x];  // exclusive prefix for this thread
#pragma unroll
    for (int j = 0; j < 4; j++) {
        int i = base + j;
        if (i < n) offsets[i] = run;
        run += v[j];
    }
}

__global__ void fill_kernel(const int* __restrict__ src, const int* __restrict__ dst,
                            const int* __restrict__ offsets, int* __restrict__ cursor,
                            int* __restrict__ csr, int E) {
    int i = blockIdx.x * blockDim.x + threadIdx.x;
    if (i < E) {
        int d = dst[i];
        int pos = atomicAdd(&cursor[d], 1);
        csr[offsets[d] + pos] = src[i];
    }
}

// ---------- per-node transform: t = x@WtE^T (fp32) ; q = x@Wq^T + qbias (fp16) ----------
template <int F_IN, int F>
__global__ __launch_bounds__(256) void transform_kernel(
        const float* __restrict__ x, const float* __restrict__ Wt,
        const float* __restrict__ Wq, const float* __restrict__ qbias,
        float* __restrict__ t, __half* __restrict__ q) {
    constexpr int NT = 256 / F;     // node rows of threads
    constexpr int NN = 4;           // nodes per thread
    constexpr int NPB = NT * NN;    // nodes per block

    __shared__ float xs[NPB][F_IN];
    __shared__ float ws[F_IN][2 * F + 1];  // transposed, padded: [k][c]

    int tid = threadIdx.x;

    // load x tile (contiguous nodes) as float4
    const float* xblk = x + (size_t)blockIdx.x * NPB * F_IN;
    for (int idx = tid * 4; idx < NPB * F_IN; idx += 256 * 4) {
        float4 v = *reinterpret_cast<const float4*>(xblk + idx);
        *reinterpret_cast<float4*>(&xs[0][0] + idx) = v;
    }
    // load weights transposed into LDS
    for (int idx = tid; idx < F * F_IN; idx += 256) {
        int c = idx / F_IN, k = idx % F_IN;
        ws[k][c] = Wt[idx];
        ws[k][c + F] = Wq[idx];
    }
    __syncthreads();

    int tx = tid % F;
    int ty = tid / F;
    int nb = ty * NN;

    float acc[NN][2];
#pragma unroll
    for (int i = 0; i < NN; i++) { acc[i][0] = 0.f; acc[i][1] = 0.f; }

#pragma unroll 4
    for (int k = 0; k < F_IN; k++) {
        float wt = ws[k][tx];
        float wq = ws[k][tx + F];
#pragma unroll
        for (int i = 0; i < NN; i++) {
            float xv = xs[nb + i][k];
            acc[i][0] = fmaf(xv, wt, acc[i][0]);
            acc[i][1] = fmaf(xv, wq, acc[i][1]);
        }
    }

    float qb = qbias[tx];
#pragma unroll
    for (int i = 0; i < NN; i++) {
        size_t node = (size_t)blockIdx.x * NPB + nb + i;
        t[node * F + tx] = acc[i][0];
        q[node * F + tx] = __float2half(acc[i][1] + qb);
    }
}

// ---------- edge max + combine + ELU (fp16 gather, packed max) ----------
// out[d][c] = indeg(d)>0 ? elu(t[d][c] + max_{s in in(d)} q[s][c]) : 0
// Each thread owns a channel PAIR (half2); F/2 threads per dst node.
template <int F>
__global__ __launch_bounds__(256) void edgemax_kernel(
        const float* __restrict__ t, const unsigned* __restrict__ q,  // q: half2 rows [N][F/2]
        const int* __restrict__ offsets, const int* __restrict__ csr,
        float* __restrict__ out, int N) {
    constexpr int NPG = F / 2;      // threads per node
    constexpr int G = 256 / NPG;    // nodes per block
    int g = threadIdx.x / NPG;
    int cp = threadIdx.x % NPG;     // channel pair index
    int nd = blockIdx.x * G + g;
    if (nd >= N) return;
    int beg = offsets[nd], end = offsets[nd + 1];

    unsigned m = HALF2_NEG_INF;
    int i = beg;
    for (; i + 1 < end; i += 2) {
        int s0 = csr[i];
        int s1 = csr[i + 1];
        unsigned v0 = q[(size_t)s0 * NPG + cp];
        unsigned v1 = q[(size_t)s1 * NPG + cp];
        m = pkmax(m, v0);
        m = pkmax(m, v1);
    }
    if (i < end) {
        int s0 = csr[i];
        m = pkmax(m, q[(size_t)s0 * NPG + cp]);
    }

    float2 r;
    if (beg < end) {
        __half2 mh = __builtin_bit_cast(__half2, m);
        float2 mf = __half22float2(mh);
        float2 tv = *reinterpret_cast<const float2*>(t + (size_t)nd * F + 2 * cp);
        r.x = elu_f(tv.x + mf.x);
        r.y = elu_f(tv.y + mf.y);
    } else {
        r.x = 0.f; r.y = 0.f;
    }
    *reinterpret_cast<float2*>(out + (size_t)nd * F + 2 * cp) = r;
}

// ---------- graph max pooling ----------
__global__ void pool_init_kernel(unsigned* __restrict__ p, int n) {
    int i = blockIdx.x * blockDim.x + threadIdx.x;
    if (i < n) p[i] = NEG_INF_MAPPED;
}

__global__ void pool_kernel(const float* __restrict__ x, const int* __restrict__ gid,
                            unsigned* __restrict__ pooled, int N) {
    const int CHUNK = 128;
    int wave = (blockIdx.x * blockDim.x + threadIdx.x) >> 6;
    int lane = threadIdx.x & 63;
    int start = wave * CHUNK;
    if (start >= N) return;
    int end = min(start + CHUNK, N);
    float m = -INFINITY;
    int cur = gid[start];
    for (int n = start; n < end; n++) {
        int g = gid[n];
        if (g != cur) {
            atomicMax(&pooled[cur * 64 + lane], fmap(m));
            cur = g;
            m = -INFINITY;
        }
        m = fmaxf(m, x[(size_t)n * 64 + lane]);
    }
    atomicMax(&pooled[cur * 64 + lane], fmap(m));
}

// ---------- FC head + log_softmax, one block (64 threads) per graph ----------
__global__ __launch_bounds__(64) void fc_kernel(
        const unsigned* __restrict__ pooled,
        const float* __restrict__ Wf1, const float* __restrict__ bf1,
        const float* __restrict__ Wf2, const float* __restrict__ bf2,
        const float* __restrict__ Wf3, const float* __restrict__ bf3,
        float* __restrict__ out) {
    int g = blockIdx.x;
    int c = threadIdx.x;
    __shared__ float x0[64], h1[64], h2[32], h3[10];

    unsigned u = pooled[g * 64 + c];
    x0[c] = (u == NEG_INF_MAPPED) ? 0.f : funmap(u);
    __syncthreads();

    float a = bf1[c];
#pragma unroll 8
    for (int k = 0; k < 64; k++) a = fmaf(Wf1[c * 64 + k], x0[k], a);
    h1[c] = elu_f(a);
    __syncthreads();

    if (c < 32) {
        float a2 = bf2[c];
#pragma unroll 8
        for (int k = 0; k < 64; k++) a2 = fmaf(Wf2[c * 64 + k], h1[k], a2);
        h2[c] = elu_f(a2);
    }
    __syncthreads();

    if (c < 10) {
        float a3 = bf3[c];
#pragma unroll 8
        for (int k = 0; k < 32; k++) a3 = fmaf(Wf3[c * 32 + k], h2[k], a3);
        h3[c] = a3;
    }
    __syncthreads();

    if (c < 10) {
        float mx = h3[0];
#pragma unroll
        for (int j = 1; j < 10; j++) mx = fmaxf(mx, h3[j]);
        float s = 0.f;
#pragma unroll
        for (int j = 0; j < 10; j++) s += expf(h3[j] - mx);
        out[g * 10 + c] = h3[c] - mx - logf(s);
    }
}

// ---------- launch ----------
extern "C" void kernel_launch(void* const* d_in, const int* in_sizes, int n_in,
                              void* d_out, int out_size, void* d_ws, size_t ws_size,
                              hipStream_t stream) {
    const float* atom = (const float*)d_in[0];
    const int* esrc = (const int*)d_in[1];
    const int* edst = (const int*)d_in[2];
    const int* gid  = (const int*)d_in[3];
    const float* Wt1 = (const float*)d_in[4];
    const float* bt1 = (const float*)d_in[5];
    const float* Wp1 = (const float*)d_in[6];
    const float* bp1 = (const float*)d_in[7];
    const float* bng = (const float*)d_in[8];
    const float* bnb = (const float*)d_in[9];
    const float* bnm = (const float*)d_in[10];
    const float* bnv = (const float*)d_in[11];
    const float* Wt2 = (const float*)d_in[12];
    const float* bt2 = (const float*)d_in[13];
    const float* Wp2 = (const float*)d_in[14];
    const float* bp2 = (const float*)d_in[15];
    const float* Wt3 = (const float*)d_in[16];
    const float* bt3 = (const float*)d_in[17];
    const float* Wp3 = (const float*)d_in[18];
    const float* bp3 = (const float*)d_in[19];
    const float* Wf1 = (const float*)d_in[20];
    const float* bf1 = (const float*)d_in[21];
    const float* Wf2 = (const float*)d_in[22];
    const float* bf2 = (const float*)d_in[23];
    const float* Wf3 = (const float*)d_in[24];
    const float* bf3 = (const float*)d_in[25];

    // workspace carve-up
    char* p = (char*)d_ws;
    auto alloc = [&](size_t bytes) -> void* {
        void* r = (void*)p;
        p += (bytes + 255) & ~(size_t)255;
        return r;
    };
    int* offsets = (int*)alloc(sizeof(int) * (N_NODES + 1));
    int* counts  = (int*)alloc(sizeof(int) * N_NODES);
    int* cursor  = (int*)alloc(sizeof(int) * N_NODES);
    int* bsums   = (int*)alloc(sizeof(int) * 128);
    int* csr     = (int*)alloc(sizeof(int) * N_EDGES);
    float* Wt1e  = (float*)alloc(sizeof(float) * 32 * 128);
    float* Wq1   = (float*)alloc(sizeof(float) * 32 * 128);
    float* qb1   = (float*)alloc(sizeof(float) * 32);
    float* Wq2   = (float*)alloc(sizeof(float) * 64 * 32);
    float* qb2   = (float*)alloc(sizeof(float) * 64);
    float* Wq3   = (float*)alloc(sizeof(float) * 64 * 64);
    float* qb3   = (float*)alloc(sizeof(float) * 64);
    float* tbuf  = (float*)alloc(sizeof(float) * (size_t)N_NODES * 64);
    __half* qbuf = (__half*)alloc(sizeof(__half) * (size_t)N_NODES * 64);
    float* xbuf  = (float*)alloc(sizeof(float) * (size_t)N_NODES * 64);
    unsigned* pooled = (unsigned*)alloc(sizeof(unsigned) * N_GRAPHS * 64);

    const int NB_SCAN = (N_NODES + SCAN_ELEMS - 1) / SCAN_ELEMS;  // 98

    // prep + CSR build
    zero2_kernel<<<(N_NODES + 255) / 256, 256, 0, stream>>>(counts, cursor, N_NODES);
    prep_kernel<<<16, 256, 0, stream>>>(Wt1, bt1, Wp1, bp1, bng, bnb, bnm, bnv,
                                        Wt2, bt2, Wp2, bp2, Wt3, bt3, Wp3, bp3,
                                        Wt1e, Wq1, qb1, Wq2, qb2, Wq3, qb3);
    count_kernel<<<(N_EDGES + 255) / 256, 256, 0, stream>>>(edst, counts, N_EDGES);
    scan_sum_kernel<<<NB_SCAN, 256, 0, stream>>>(counts, bsums, N_NODES);
    scan_top_kernel<<<1, 64, 0, stream>>>(bsums, NB_SCAN, offsets, N_NODES);
    scan_out_kernel<<<NB_SCAN, 256, 0, stream>>>(counts, bsums, offsets, N_NODES);
    fill_kernel<<<(N_EDGES + 255) / 256, 256, 0, stream>>>(esrc, edst, offsets, cursor, csr, N_EDGES);

    // layer 1: 128 -> 32 (BN folded)
    transform_kernel<128, 32><<<N_NODES / 32, 256, 0, stream>>>(atom, Wt1e, Wq1, qb1, tbuf, qbuf);
    edgemax_kernel<32><<<N_NODES / 16, 256, 0, stream>>>(tbuf, (const unsigned*)qbuf, offsets, csr, xbuf, N_NODES);

    // layer 2: 32 -> 64
    transform_kernel<32, 64><<<N_NODES / 16, 256, 0, stream>>>(xbuf, Wt2, Wq2, qb2, tbuf, qbuf);
    edgemax_kernel<64><<<N_NODES / 8, 256, 0, stream>>>(tbuf, (const unsigned*)qbuf, offsets, csr, xbuf, N_NODES);

    // layer 3: 64 -> 64
    transform_kernel<64, 64><<<N_NODES / 16, 256, 0, stream>>>(xbuf, Wt3, Wq3, qb3, tbuf, qbuf);
    edgemax_kernel<64><<<N_NODES / 8, 256, 0, stream>>>(tbuf, (const unsigned*)qbuf, offsets, csr, xbuf, N_NODES);

    // graph pooling
    pool_init_kernel<<<(N_GRAPHS * 64 + 255) / 256, 256, 0, stream>>>(pooled, N_GRAPHS * 64);
    {
        int waves = (N_NODES + 127) / 128;
        int blocks = (waves + 3) / 4;  // 4 waves per 256-thread block
        pool_kernel<<<blocks, 256, 0, stream>>>(xbuf, gid, pooled, N_NODES);
    }

    // FC head
    fc_kernel<<<N_GRAPHS, 64, 0, stream>>>(pooled, Wf1, bf1, Wf2, bf2, Wf3, bf3, (float*)d_out);
}

// Round 3
// 310.216 us; speedup vs baseline: 1.4722x; 1.2128x over previous
//
#include <hip/hip_runtime.h>
#include <hip/hip_fp16.h>
#include <math.h>

#define N_NODES 100000
#define N_EDGES 1000000
#define N_GRAPHS 1024
#define BN_EPS 1e-5f

#define BUCKET_NODES 128
#define NB_BUCKETS ((N_NODES + BUCKET_NODES - 1) / BUCKET_NODES)  // 782
#define BUCKET_CAP 3072
#define SCAT_CHUNK 16384

// ---------- helpers ----------
static __device__ __forceinline__ float elu_f(float v) {
    return v > 0.f ? v : expm1f(v);
}

// packed fp16 max (2 halves) — gfx950 v_pk_max_f16
static __device__ __forceinline__ unsigned pkmax(unsigned a, unsigned b) {
    unsigned r;
    asm("v_pk_max_f16 %0, %1, %2" : "=v"(r) : "v"(a), "v"(b));
    return r;
}
#define HALF2_NEG_INF 0xFC00FC00u

// monotone float -> uint mapping (order-preserving) for atomicMax on floats
static __device__ __forceinline__ unsigned fmap(float f) {
    unsigned u = __float_as_uint(f);
    return (u & 0x80000000u) ? ~u : (u | 0x80000000u);
}
static __device__ __forceinline__ float funmap(unsigned u) {
    unsigned b = (u & 0x80000000u) ? (u & 0x7FFFFFFFu) : ~u;
    return __uint_as_float(b);
}
#define NEG_INF_MAPPED 0x007FFFFFu  // fmap(-inf)

// ---------- prep: fold BN, compute Wq = Wp - Wt, combined biases ----------
__global__ void prep_kernel(const float* __restrict__ Wt1, const float* __restrict__ bt1,
                            const float* __restrict__ Wp1, const float* __restrict__ bp1,
                            const float* __restrict__ gamma, const float* __restrict__ beta,
                            const float* __restrict__ mean,  const float* __restrict__ var,
                            const float* __restrict__ Wt2, const float* __restrict__ bt2,
                            const float* __restrict__ Wp2, const float* __restrict__ bp2,
                            const float* __restrict__ Wt3, const float* __restrict__ bt3,
                            const float* __restrict__ Wp3, const float* __restrict__ bp3,
                            float* __restrict__ Wt1e, float* __restrict__ Wq1, float* __restrict__ qb1,
                            float* __restrict__ Wq2,  float* __restrict__ qb2,
                            float* __restrict__ Wq3,  float* __restrict__ qb3) {
    int i = blockIdx.x * blockDim.x + threadIdx.x;
    if (i < 32 * 128) {
        int c = i / 128;
        float s = gamma[c] * rsqrtf(var[c] + BN_EPS);
        Wt1e[i] = Wt1[i] * s;
        Wq1[i] = (Wp1[i] - Wt1[i]) * s;
    }
    if (i < 32) {
        float s = gamma[i] * rsqrtf(var[i] + BN_EPS);
        qb1[i] = (bt1[i] + bp1[i]) * s + beta[i] - mean[i] * s;
    }
    if (i < 64 * 32) Wq2[i] = Wp2[i] - Wt2[i];
    if (i < 64) qb2[i] = bt2[i] + bp2[i];
    if (i < 64 * 64) Wq3[i] = Wp3[i] - Wt3[i];
    if (i < 64) qb3[i] = bt3[i] + bp3[i];
}

// ---------- binned CSR build ----------
// bucket = dst >> 7 (128 nodes per bucket). Packed edge: (src << 7) | (dst & 127).

__global__ __launch_bounds__(256) void bucket_count_kernel(const int* __restrict__ edst,
                                                           int* __restrict__ bcnt, int E) {
    __shared__ int h[NB_BUCKETS];
    for (int i = threadIdx.x; i < NB_BUCKETS; i += 256) h[i] = 0;
    __syncthreads();
    int stride = gridDim.x * 256;
    for (int i = blockIdx.x * 256 + threadIdx.x; i < E; i += stride)
        atomicAdd(&h[edst[i] >> 7], 1);
    __syncthreads();
    for (int i = threadIdx.x; i < NB_BUCKETS; i += 256) {
        int c = h[i];
        if (c) atomicAdd(&bcnt[i], c);
    }
}

// one block, 1024 threads: exclusive scan of bcnt[NB_BUCKETS] -> base[NB_BUCKETS+1]
__global__ __launch_bounds__(1024) void bucket_scan_kernel(const int* __restrict__ bcnt,
                                                           int* __restrict__ base) {
    __shared__ int s[1024];
    int t = threadIdx.x;
    int v = (t < NB_BUCKETS) ? bcnt[t] : 0;
    s[t] = v;
    __syncthreads();
    for (int off = 1; off < 1024; off <<= 1) {
        int u = (t >= off) ? s[t - off] : 0;
        __syncthreads();
        s[t] += u;
        __syncthreads();
    }
    if (t < NB_BUCKETS) base[t + 1] = s[t];
    if (t == 0) base[0] = 0;
}

__global__ __launch_bounds__(256) void scatter_kernel(const int* __restrict__ esrc,
                                                      const int* __restrict__ edst,
                                                      const int* __restrict__ base,
                                                      int* __restrict__ cursor,
                                                      unsigned* __restrict__ binned, int E) {
    __shared__ int hist[NB_BUCKETS];
    __shared__ int lbase[NB_BUCKETS];
    int begE = blockIdx.x * SCAT_CHUNK;
    int endE = min(begE + SCAT_CHUNK, E);
    for (int i = threadIdx.x; i < NB_BUCKETS; i += 256) hist[i] = 0;
    __syncthreads();
    for (int i = begE + threadIdx.x; i < endE; i += 256)
        atomicAdd(&hist[edst[i] >> 7], 1);
    __syncthreads();
    for (int i = threadIdx.x; i < NB_BUCKETS; i += 256) {
        int c = hist[i];
        lbase[i] = c ? atomicAdd(&cursor[i], c) : 0;
        hist[i] = 0;  // reuse as local cursor
    }
    __syncthreads();
    for (int i = begE + threadIdx.x; i < endE; i += 256) {
        int d = edst[i];
        int b = d >> 7;
        int pos = lbase[b] + atomicAdd(&hist[b], 1);
        binned[base[b] + pos] = ((unsigned)esrc[i] << 7) | (unsigned)(d & 127);
    }
}

// one block per bucket: LDS-local CSR build, coalesced csr/offsets writes.
__global__ __launch_bounds__(256) void bucket_build_kernel(const unsigned* __restrict__ binned,
                                                           const int* __restrict__ base,
                                                           int* __restrict__ offsets,
                                                           int* __restrict__ csr) {
    __shared__ unsigned stage[BUCKET_CAP];
    __shared__ int srcLDS[BUCKET_CAP];
    __shared__ int cnt[BUCKET_NODES];   // counts, then cursors
    __shared__ int sc[BUCKET_NODES];    // scan buffer
    __shared__ int loff[BUCKET_NODES];  // local exclusive offsets

    int b = blockIdx.x;
    int ebeg = base[b], eend = base[b + 1];
    int ne = eend - ebeg;
    int tid = threadIdx.x;

    if (tid < BUCKET_NODES) cnt[tid] = 0;
    __syncthreads();
    for (int i = tid; i < ne; i += 256) {
        unsigned e = binned[ebeg + i];
        stage[i] = e;
        atomicAdd(&cnt[e & 127], 1);
    }
    __syncthreads();
    // scan cnt[128] (Hillis-Steele, barrier-uniform)
    int v = (tid < BUCKET_NODES) ? cnt[tid] : 0;
    if (tid < BUCKET_NODES) sc[tid] = v;
    __syncthreads();
    for (int off = 1; off < BUCKET_NODES; off <<= 1) {
        int u = (tid < BUCKET_NODES && tid >= off) ? sc[tid - off] : 0;
        __syncthreads();
        if (tid < BUCKET_NODES) sc[tid] += u;
        __syncthreads();
    }
    if (tid < BUCKET_NODES) {
        loff[tid] = sc[tid] - v;  // exclusive
        cnt[tid] = 0;             // reuse as cursor
    }
    __syncthreads();
    // write global node offsets (coalesced)
    int gnode = b * BUCKET_NODES + tid;
    if (tid < BUCKET_NODES && gnode < N_NODES) offsets[gnode] = ebeg + loff[tid];
    if (b == gridDim.x - 1 && tid == 0) offsets[N_NODES] = eend;
    // local scatter
    for (int i = tid; i < ne; i += 256) {
        unsigned e = stage[i];
        int ln = e & 127;
        int slot = loff[ln] + atomicAdd(&cnt[ln], 1);
        srcLDS[slot] = (int)(e >> 7);
    }
    __syncthreads();
    // coalesced csr dump
    for (int i = tid; i < ne; i += 256) csr[ebeg + i] = srcLDS[i];
}

// ---------- per-node transform: t = x@WtE^T (fp32) ; q = x@Wq^T + qbias (fp16) ----------
template <int F_IN, int F>
__global__ __launch_bounds__(256) void transform_kernel(
        const float* __restrict__ x, const float* __restrict__ Wt,
        const float* __restrict__ Wq, const float* __restrict__ qbias,
        float* __restrict__ t, __half* __restrict__ q) {
    constexpr int NT = 256 / F;     // node rows of threads
    constexpr int NN = 4;           // nodes per thread
    constexpr int NPB = NT * NN;    // nodes per block

    __shared__ float xs[NPB][F_IN];
    __shared__ float ws[F_IN][2 * F + 1];  // transposed, padded: [k][c]

    int tid = threadIdx.x;

    const float* xblk = x + (size_t)blockIdx.x * NPB * F_IN;
    for (int idx = tid * 4; idx < NPB * F_IN; idx += 256 * 4) {
        float4 v = *reinterpret_cast<const float4*>(xblk + idx);
        *reinterpret_cast<float4*>(&xs[0][0] + idx) = v;
    }
    for (int idx = tid; idx < F * F_IN; idx += 256) {
        int c = idx / F_IN, k = idx % F_IN;
        ws[k][c] = Wt[idx];
        ws[k][c + F] = Wq[idx];
    }
    __syncthreads();

    int tx = tid % F;
    int ty = tid / F;
    int nb = ty * NN;

    float acc[NN][2];
#pragma unroll
    for (int i = 0; i < NN; i++) { acc[i][0] = 0.f; acc[i][1] = 0.f; }

#pragma unroll 4
    for (int k = 0; k < F_IN; k++) {
        float wt = ws[k][tx];
        float wq = ws[k][tx + F];
#pragma unroll
        for (int i = 0; i < NN; i++) {
            float xv = xs[nb + i][k];
            acc[i][0] = fmaf(xv, wt, acc[i][0]);
            acc[i][1] = fmaf(xv, wq, acc[i][1]);
        }
    }

    float qb = qbias[tx];
#pragma unroll
    for (int i = 0; i < NN; i++) {
        size_t node = (size_t)blockIdx.x * NPB + nb + i;
        t[node * F + tx] = acc[i][0];
        q[node * F + tx] = __float2half(acc[i][1] + qb);
    }
}

// ---------- edge max + combine + ELU (fp16 gather, packed max, 4x unroll) ----------
template <int F>
__global__ __launch_bounds__(256) void edgemax_kernel(
        const float* __restrict__ t, const unsigned* __restrict__ q,  // q: half2 rows [N][F/2]
        const int* __restrict__ offsets, const int* __restrict__ csr,
        float* __restrict__ out, int N) {
    constexpr int NPG = F / 2;      // threads per node
    constexpr int G = 256 / NPG;    // nodes per block
    int g = threadIdx.x / NPG;
    int cp = threadIdx.x % NPG;     // channel pair index
    int nd = blockIdx.x * G + g;
    if (nd >= N) return;
    int beg = offsets[nd], end = offsets[nd + 1];

    unsigned m0 = HALF2_NEG_INF, m1 = HALF2_NEG_INF;
    int i = beg;
    for (; i + 3 < end; i += 4) {
        int s0 = csr[i], s1 = csr[i + 1], s2 = csr[i + 2], s3 = csr[i + 3];
        unsigned v0 = q[(size_t)s0 * NPG + cp];
        unsigned v1 = q[(size_t)s1 * NPG + cp];
        unsigned v2 = q[(size_t)s2 * NPG + cp];
        unsigned v3 = q[(size_t)s3 * NPG + cp];
        m0 = pkmax(m0, pkmax(v0, v1));
        m1 = pkmax(m1, pkmax(v2, v3));
    }
    for (; i < end; i++) {
        m0 = pkmax(m0, q[(size_t)csr[i] * NPG + cp]);
    }
    unsigned m = pkmax(m0, m1);

    float2 r;
    if (beg < end) {
        __half2 mh = __builtin_bit_cast(__half2, m);
        float2 mf = __half22float2(mh);
        float2 tv = *reinterpret_cast<const float2*>(t + (size_t)nd * F + 2 * cp);
        r.x = elu_f(tv.x + mf.x);
        r.y = elu_f(tv.y + mf.y);
    } else {
        r.x = 0.f; r.y = 0.f;
    }
    *reinterpret_cast<float2*>(out + (size_t)nd * F + 2 * cp) = r;
}

// ---------- graph max pooling ----------
__global__ void pool_init_kernel(unsigned* __restrict__ p, int n) {
    int i = blockIdx.x * blockDim.x + threadIdx.x;
    if (i < n) p[i] = NEG_INF_MAPPED;
}

__global__ void pool_kernel(const float* __restrict__ x, const int* __restrict__ gid,
                            unsigned* __restrict__ pooled, int N) {
    const int CHUNK = 64;
    int wave = (blockIdx.x * blockDim.x + threadIdx.x) >> 6;
    int lane = threadIdx.x & 63;
    int start = wave * CHUNK;
    if (start >= N) return;
    int end = min(start + CHUNK, N);
    float m = -INFINITY;
    int cur = gid[start];
    for (int n = start; n < end; n++) {
        int g = gid[n];
        if (g != cur) {
            atomicMax(&pooled[cur * 64 + lane], fmap(m));
            cur = g;
            m = -INFINITY;
        }
        m = fmaxf(m, x[(size_t)n * 64 + lane]);
    }
    atomicMax(&pooled[cur * 64 + lane], fmap(m));
}

// ---------- FC head + log_softmax, one block (64 threads) per graph ----------
__global__ __launch_bounds__(64) void fc_kernel(
        const unsigned* __restrict__ pooled,
        const float* __restrict__ Wf1, const float* __restrict__ bf1,
        const float* __restrict__ Wf2, const float* __restrict__ bf2,
        const float* __restrict__ Wf3, const float* __restrict__ bf3,
        float* __restrict__ out) {
    int g = blockIdx.x;
    int c = threadIdx.x;
    __shared__ float x0[64], h1[64], h2[32], h3[10];

    unsigned u = pooled[g * 64 + c];
    x0[c] = (u == NEG_INF_MAPPED) ? 0.f : funmap(u);
    __syncthreads();

    float a = bf1[c];
#pragma unroll 8
    for (int k = 0; k < 64; k++) a = fmaf(Wf1[c * 64 + k], x0[k], a);
    h1[c] = elu_f(a);
    __syncthreads();

    if (c < 32) {
        float a2 = bf2[c];
#pragma unroll 8
        for (int k = 0; k < 64; k++) a2 = fmaf(Wf2[c * 64 + k], h1[k], a2);
        h2[c] = elu_f(a2);
    }
    __syncthreads();

    if (c < 10) {
        float a3 = bf3[c];
#pragma unroll 8
        for (int k = 0; k < 32; k++) a3 = fmaf(Wf3[c * 32 + k], h2[k], a3);
        h3[c] = a3;
    }
    __syncthreads();

    if (c < 10) {
        float mx = h3[0];
#pragma unroll
        for (int j = 1; j < 10; j++) mx = fmaxf(mx, h3[j]);
        float s = 0.f;
#pragma unroll
        for (int j = 0; j < 10; j++) s += expf(h3[j] - mx);
        out[g * 10 + c] = h3[c] - mx - logf(s);
    }
}

// ---------- launch ----------
extern "C" void kernel_launch(void* const* d_in, const int* in_sizes, int n_in,
                              void* d_out, int out_size, void* d_ws, size_t ws_size,
                              hipStream_t stream) {
    const float* atom = (const float*)d_in[0];
    const int* esrc = (const int*)d_in[1];
    const int* edst = (const int*)d_in[2];
    const int* gid  = (const int*)d_in[3];
    const float* Wt1 = (const float*)d_in[4];
    const float* bt1 = (const float*)d_in[5];
    const float* Wp1 = (const float*)d_in[6];
    const float* bp1 = (const float*)d_in[7];
    const float* bng = (const float*)d_in[8];
    const float* bnb = (const float*)d_in[9];
    const float* bnm = (const float*)d_in[10];
    const float* bnv = (const float*)d_in[11];
    const float* Wt2 = (const float*)d_in[12];
    const float* bt2 = (const float*)d_in[13];
    const float* Wp2 = (const float*)d_in[14];
    const float* bp2 = (const float*)d_in[15];
    const float* Wt3 = (const float*)d_in[16];
    const float* bt3 = (const float*)d_in[17];
    const float* Wp3 = (const float*)d_in[18];
    const float* bp3 = (const float*)d_in[19];
    const float* Wf1 = (const float*)d_in[20];
    const float* bf1 = (const float*)d_in[21];
    const float* Wf2 = (const float*)d_in[22];
    const float* bf2 = (const float*)d_in[23];
    const float* Wf3 = (const float*)d_in[24];
    const float* bf3 = (const float*)d_in[25];

    // workspace carve-up
    char* p = (char*)d_ws;
    auto alloc = [&](size_t bytes) -> void* {
        void* r = (void*)p;
        p += (bytes + 255) & ~(size_t)255;
        return r;
    };
    int* offsets    = (int*)alloc(sizeof(int) * (N_NODES + 1));
    int* bcnt       = (int*)alloc(sizeof(int) * NB_BUCKETS);
    int* bbase      = (int*)alloc(sizeof(int) * (NB_BUCKETS + 1));
    int* bcursor    = (int*)alloc(sizeof(int) * NB_BUCKETS);
    unsigned* binned = (unsigned*)alloc(sizeof(unsigned) * N_EDGES);
    int* csr        = (int*)alloc(sizeof(int) * N_EDGES);
    float* Wt1e  = (float*)alloc(sizeof(float) * 32 * 128);
    float* Wq1   = (float*)alloc(sizeof(float) * 32 * 128);
    float* qb1   = (float*)alloc(sizeof(float) * 32);
    float* Wq2   = (float*)alloc(sizeof(float) * 64 * 32);
    float* qb2   = (float*)alloc(sizeof(float) * 64);
    float* Wq3   = (float*)alloc(sizeof(float) * 64 * 64);
    float* qb3   = (float*)alloc(sizeof(float) * 64);
    float* tbuf  = (float*)alloc(sizeof(float) * (size_t)N_NODES * 64);
    __half* qbuf = (__half*)alloc(sizeof(__half) * (size_t)N_NODES * 64);
    float* xbuf  = (float*)alloc(sizeof(float) * (size_t)N_NODES * 64);
    unsigned* pooled = (unsigned*)alloc(sizeof(unsigned) * N_GRAPHS * 64);

    // CSR build (binned, coalesced)
    hipMemsetAsync(bcnt, 0, sizeof(int) * NB_BUCKETS, stream);
    hipMemsetAsync(bcursor, 0, sizeof(int) * NB_BUCKETS, stream);
    prep_kernel<<<16, 256, 0, stream>>>(Wt1, bt1, Wp1, bp1, bng, bnb, bnm, bnv,
                                        Wt2, bt2, Wp2, bp2, Wt3, bt3, Wp3, bp3,
                                        Wt1e, Wq1, qb1, Wq2, qb2, Wq3, qb3);
    bucket_count_kernel<<<128, 256, 0, stream>>>(edst, bcnt, N_EDGES);
    bucket_scan_kernel<<<1, 1024, 0, stream>>>(bcnt, bbase);
    scatter_kernel<<<(N_EDGES + SCAT_CHUNK - 1) / SCAT_CHUNK, 256, 0, stream>>>(
        esrc, edst, bbase, bcursor, binned, N_EDGES);
    bucket_build_kernel<<<NB_BUCKETS, 256, 0, stream>>>(binned, bbase, offsets, csr);

    // layer 1: 128 -> 32 (BN folded)
    transform_kernel<128, 32><<<N_NODES / 32, 256, 0, stream>>>(atom, Wt1e, Wq1, qb1, tbuf, qbuf);
    edgemax_kernel<32><<<N_NODES / 16, 256, 0, stream>>>(tbuf, (const unsigned*)qbuf, offsets, csr, xbuf, N_NODES);

    // layer 2: 32 -> 64
    transform_kernel<32, 64><<<N_NODES / 16, 256, 0, stream>>>(xbuf, Wt2, Wq2, qb2, tbuf, qbuf);
    edgemax_kernel<64><<<N_NODES / 8, 256, 0, stream>>>(tbuf, (const unsigned*)qbuf, offsets, csr, xbuf, N_NODES);

    // layer 3: 64 -> 64
    transform_kernel<64, 64><<<N_NODES / 16, 256, 0, stream>>>(xbuf, Wt3, Wq3, qb3, tbuf, qbuf);
    edgemax_kernel<64><<<N_NODES / 8, 256, 0, stream>>>(tbuf, (const unsigned*)qbuf, offsets, csr, xbuf, N_NODES);

    // graph pooling
    pool_init_kernel<<<(N_GRAPHS * 64 + 255) / 256, 256, 0, stream>>>(pooled, N_GRAPHS * 64);
    {
        int waves = (N_NODES + 63) / 64;
        int blocks = (waves + 3) / 4;  // 4 waves per 256-thread block
        pool_kernel<<<blocks, 256, 0, stream>>>(xbuf, gid, pooled, N_NODES);
    }

    // FC head
    fc_kernel<<<N_GRAPHS, 64, 0, stream>>>(pooled, Wf1, bf1, Wf2, bf2, Wf3, bf3, (float*)d_out);
}

// Round 4
// 282.452 us; speedup vs baseline: 1.6169x; 1.0983x over previous
//
#include <hip/hip_runtime.h>
#include <hip/hip_fp16.h>
#include <math.h>

#define N_NODES 100000
#define N_EDGES 1000000
#define N_GRAPHS 1024
#define BN_EPS 1e-5f

#define BUCKET_NODES 128
#define NB_BUCKETS ((N_NODES + BUCKET_NODES - 1) / BUCKET_NODES)  // 782
#define BUCKET_CAP 3072
#define SCAT_CHUNK 2048

// ---------- helpers ----------
static __device__ __forceinline__ float elu_f(float v) {
    return v > 0.f ? v : expm1f(v);
}

// packed fp16 max (2 halves) — gfx950 v_pk_max_f16
static __device__ __forceinline__ unsigned pkmax(unsigned a, unsigned b) {
    unsigned r;
    asm("v_pk_max_f16 %0, %1, %2" : "=v"(r) : "v"(a), "v"(b));
    return r;
}
#define HALF2_NEG_INF 0xFC00FC00u

// monotone float -> uint mapping (order-preserving) for atomicMax on floats
static __device__ __forceinline__ unsigned fmap(float f) {
    unsigned u = __float_as_uint(f);
    return (u & 0x80000000u) ? ~u : (u | 0x80000000u);
}
static __device__ __forceinline__ float funmap(unsigned u) {
    unsigned b = (u & 0x80000000u) ? (u & 0x7FFFFFFFu) : ~u;
    return __uint_as_float(b);
}
#define NEG_INF_MAPPED 0x007FFFFFu  // fmap(-inf)

// ---------- prep: fold BN, compute Wq = Wp - Wt, combined biases ----------
__global__ void prep_kernel(const float* __restrict__ Wt1, const float* __restrict__ bt1,
                            const float* __restrict__ Wp1, const float* __restrict__ bp1,
                            const float* __restrict__ gamma, const float* __restrict__ beta,
                            const float* __restrict__ mean,  const float* __restrict__ var,
                            const float* __restrict__ Wt2, const float* __restrict__ bt2,
                            const float* __restrict__ Wp2, const float* __restrict__ bp2,
                            const float* __restrict__ Wt3, const float* __restrict__ bt3,
                            const float* __restrict__ Wp3, const float* __restrict__ bp3,
                            float* __restrict__ Wt1e, float* __restrict__ Wq1, float* __restrict__ qb1,
                            float* __restrict__ Wq2,  float* __restrict__ qb2,
                            float* __restrict__ Wq3,  float* __restrict__ qb3) {
    int i = blockIdx.x * blockDim.x + threadIdx.x;
    if (i < 32 * 128) {
        int c = i / 128;
        float s = gamma[c] * rsqrtf(var[c] + BN_EPS);
        Wt1e[i] = Wt1[i] * s;
        Wq1[i] = (Wp1[i] - Wt1[i]) * s;
    }
    if (i < 32) {
        float s = gamma[i] * rsqrtf(var[i] + BN_EPS);
        qb1[i] = (bt1[i] + bp1[i]) * s + beta[i] - mean[i] * s;
    }
    if (i < 64 * 32) Wq2[i] = Wp2[i] - Wt2[i];
    if (i < 64) qb2[i] = bt2[i] + bp2[i];
    if (i < 64 * 64) Wq3[i] = Wp3[i] - Wt3[i];
    if (i < 64) qb3[i] = bt3[i] + bp3[i];
}

// ---------- binned CSR build ----------
// bucket = dst >> 7 (128 nodes per bucket). Packed edge: (src << 7) | (dst & 127).

__global__ __launch_bounds__(256) void bucket_count_kernel(const int* __restrict__ edst,
                                                           int* __restrict__ bcnt, int E) {
    __shared__ int h[NB_BUCKETS];
    for (int i = threadIdx.x; i < NB_BUCKETS; i += 256) h[i] = 0;
    __syncthreads();
    int stride = gridDim.x * 256;
    for (int i = blockIdx.x * 256 + threadIdx.x; i < E; i += stride)
        atomicAdd(&h[edst[i] >> 7], 1);
    __syncthreads();
    for (int i = threadIdx.x; i < NB_BUCKETS; i += 256) {
        int c = h[i];
        if (c) atomicAdd(&bcnt[i], c);
    }
}

// one block, 1024 threads: exclusive scan of bcnt[NB_BUCKETS] -> base[NB_BUCKETS+1]
__global__ __launch_bounds__(1024) void bucket_scan_kernel(const int* __restrict__ bcnt,
                                                           int* __restrict__ base) {
    __shared__ int s[1024];
    int t = threadIdx.x;
    int v = (t < NB_BUCKETS) ? bcnt[t] : 0;
    s[t] = v;
    __syncthreads();
    for (int off = 1; off < 1024; off <<= 1) {
        int u = (t >= off) ? s[t - off] : 0;
        __syncthreads();
        s[t] += u;
        __syncthreads();
    }
    if (t < NB_BUCKETS) base[t + 1] = s[t];
    if (t == 0) base[0] = 0;
}

// LDS-staged scatter: one global read per edge, high-occupancy grid.
__global__ __launch_bounds__(256) void scatter_kernel(const int* __restrict__ esrc,
                                                      const int* __restrict__ edst,
                                                      const int* __restrict__ base,
                                                      int* __restrict__ cursor,
                                                      unsigned* __restrict__ binned, int E) {
    __shared__ int hist[NB_BUCKETS];
    __shared__ int lbase[NB_BUCKETS];
    __shared__ unsigned pk[SCAT_CHUNK];
    __shared__ unsigned short bk[SCAT_CHUNK];
    int begE = blockIdx.x * SCAT_CHUNK;
    int endE = min(begE + SCAT_CHUNK, E);
    int n = endE - begE;
    for (int i = threadIdx.x; i < NB_BUCKETS; i += 256) hist[i] = 0;
    __syncthreads();
    for (int i = threadIdx.x; i < n; i += 256) {
        int d = edst[begE + i];
        int s = esrc[begE + i];
        int b = d >> 7;
        pk[i] = ((unsigned)s << 7) | (unsigned)(d & 127);
        bk[i] = (unsigned short)b;
        atomicAdd(&hist[b], 1);
    }
    __syncthreads();
    for (int i = threadIdx.x; i < NB_BUCKETS; i += 256) {
        int c = hist[i];
        lbase[i] = c ? (base[i] + atomicAdd(&cursor[i], c)) : 0;
        hist[i] = 0;  // reuse as local cursor
    }
    __syncthreads();
    for (int i = threadIdx.x; i < n; i += 256) {
        int b = bk[i];
        int pos = lbase[b] + atomicAdd(&hist[b], 1);
        binned[pos] = pk[i];
    }
}

// one block per bucket: LDS-local CSR build, coalesced csr/offsets writes.
__global__ __launch_bounds__(256) void bucket_build_kernel(const unsigned* __restrict__ binned,
                                                           const int* __restrict__ base,
                                                           int* __restrict__ offsets,
                                                           int* __restrict__ csr) {
    __shared__ unsigned stage[BUCKET_CAP];
    __shared__ int srcLDS[BUCKET_CAP];
    __shared__ int cnt[BUCKET_NODES];   // counts, then cursors
    __shared__ int sc[BUCKET_NODES];    // scan buffer
    __shared__ int loff[BUCKET_NODES];  // local exclusive offsets

    int b = blockIdx.x;
    int ebeg = base[b], eend = base[b + 1];
    int ne = eend - ebeg;
    int tid = threadIdx.x;

    if (tid < BUCKET_NODES) cnt[tid] = 0;
    __syncthreads();
    for (int i = tid; i < ne; i += 256) {
        unsigned e = binned[ebeg + i];
        stage[i] = e;
        atomicAdd(&cnt[e & 127], 1);
    }
    __syncthreads();
    // scan cnt[128] (Hillis-Steele, barrier-uniform)
    int v = (tid < BUCKET_NODES) ? cnt[tid] : 0;
    if (tid < BUCKET_NODES) sc[tid] = v;
    __syncthreads();
    for (int off = 1; off < BUCKET_NODES; off <<= 1) {
        int u = (tid < BUCKET_NODES && tid >= off) ? sc[tid - off] : 0;
        __syncthreads();
        if (tid < BUCKET_NODES) sc[tid] += u;
        __syncthreads();
    }
    if (tid < BUCKET_NODES) {
        loff[tid] = sc[tid] - v;  // exclusive
        cnt[tid] = 0;             // reuse as cursor
    }
    __syncthreads();
    // write global node offsets (coalesced)
    int gnode = b * BUCKET_NODES + tid;
    if (tid < BUCKET_NODES && gnode < N_NODES) offsets[gnode] = ebeg + loff[tid];
    if (b == gridDim.x - 1 && tid == 0) offsets[N_NODES] = eend;
    // local scatter
    for (int i = tid; i < ne; i += 256) {
        unsigned e = stage[i];
        int ln = e & 127;
        int slot = loff[ln] + atomicAdd(&cnt[ln], 1);
        srcLDS[slot] = (int)(e >> 7);
    }
    __syncthreads();
    // coalesced csr dump
    for (int i = tid; i < ne; i += 256) csr[ebeg + i] = srcLDS[i];
}

// ---------- per-node transform: t = x@WtE^T (fp32) ; q = x@Wq^T + qbias (fp16) ----------
template <int F_IN, int F>
__global__ __launch_bounds__(256) void transform_kernel(
        const float* __restrict__ x, const float* __restrict__ Wt,
        const float* __restrict__ Wq, const float* __restrict__ qbias,
        float* __restrict__ t, __half* __restrict__ q) {
    constexpr int NT = 256 / F;     // node rows of threads
    constexpr int NN = 4;           // nodes per thread
    constexpr int NPB = NT * NN;    // nodes per block

    __shared__ float xs[NPB][F_IN];
    __shared__ float ws[F_IN][2 * F + 1];  // transposed, padded: [k][c]

    int tid = threadIdx.x;

    const float* xblk = x + (size_t)blockIdx.x * NPB * F_IN;
    for (int idx = tid * 4; idx < NPB * F_IN; idx += 256 * 4) {
        float4 v = *reinterpret_cast<const float4*>(xblk + idx);
        *reinterpret_cast<float4*>(&xs[0][0] + idx) = v;
    }
    for (int idx = tid; idx < F * F_IN; idx += 256) {
        int c = idx / F_IN, k = idx % F_IN;
        ws[k][c] = Wt[idx];
        ws[k][c + F] = Wq[idx];
    }
    __syncthreads();

    int tx = tid % F;
    int ty = tid / F;
    int nb = ty * NN;

    float acc[NN][2];
#pragma unroll
    for (int i = 0; i < NN; i++) { acc[i][0] = 0.f; acc[i][1] = 0.f; }

#pragma unroll 4
    for (int k = 0; k < F_IN; k++) {
        float wt = ws[k][tx];
        float wq = ws[k][tx + F];
#pragma unroll
        for (int i = 0; i < NN; i++) {
            float xv = xs[nb + i][k];
            acc[i][0] = fmaf(xv, wt, acc[i][0]);
            acc[i][1] = fmaf(xv, wq, acc[i][1]);
        }
    }

    float qb = qbias[tx];
#pragma unroll
    for (int i = 0; i < NN; i++) {
        size_t node = (size_t)blockIdx.x * NPB + nb + i;
        t[node * F + tx] = acc[i][0];
        q[node * F + tx] = __float2half(acc[i][1] + qb);
    }
}

// ---------- edge max + combine + ELU (fp16 gather, packed max, 4x unroll) ----------
template <int F>
__global__ __launch_bounds__(256) void edgemax_kernel(
        const float* __restrict__ t, const unsigned* __restrict__ q,  // q: half2 rows [N][F/2]
        const int* __restrict__ offsets, const int* __restrict__ csr,
        float* __restrict__ out, int N) {
    constexpr int NPG = F / 2;      // threads per node
    constexpr int G = 256 / NPG;    // nodes per block
    int g = threadIdx.x / NPG;
    int cp = threadIdx.x % NPG;     // channel pair index
    int nd = blockIdx.x * G + g;
    if (nd >= N) return;
    int beg = offsets[nd], end = offsets[nd + 1];

    unsigned m0 = HALF2_NEG_INF, m1 = HALF2_NEG_INF;
    int i = beg;
    for (; i + 3 < end; i += 4) {
        int s0 = csr[i], s1 = csr[i + 1], s2 = csr[i + 2], s3 = csr[i + 3];
        unsigned v0 = q[(size_t)s0 * NPG + cp];
        unsigned v1 = q[(size_t)s1 * NPG + cp];
        unsigned v2 = q[(size_t)s2 * NPG + cp];
        unsigned v3 = q[(size_t)s3 * NPG + cp];
        m0 = pkmax(m0, pkmax(v0, v1));
        m1 = pkmax(m1, pkmax(v2, v3));
    }
    for (; i < end; i++) {
        m0 = pkmax(m0, q[(size_t)csr[i] * NPG + cp]);
    }
    unsigned m = pkmax(m0, m1);

    float2 r;
    if (beg < end) {
        __half2 mh = __builtin_bit_cast(__half2, m);
        float2 mf = __half22float2(mh);
        float2 tv = *reinterpret_cast<const float2*>(t + (size_t)nd * F + 2 * cp);
        r.x = elu_f(tv.x + mf.x);
        r.y = elu_f(tv.y + mf.y);
    } else {
        r.x = 0.f; r.y = 0.f;
    }
    *reinterpret_cast<float2*>(out + (size_t)nd * F + 2 * cp) = r;
}

// ---------- graph max pooling ----------
__global__ void pool_init_kernel(unsigned* __restrict__ p, int n) {
    int i = blockIdx.x * blockDim.x + threadIdx.x;
    if (i < n) p[i] = NEG_INF_MAPPED;
}

__global__ void pool_kernel(const float* __restrict__ x, const int* __restrict__ gid,
                            unsigned* __restrict__ pooled, int N) {
    const int CHUNK = 64;
    int wave = (blockIdx.x * blockDim.x + threadIdx.x) >> 6;
    int lane = threadIdx.x & 63;
    int start = wave * CHUNK;
    if (start >= N) return;
    int end = min(start + CHUNK, N);
    float m = -INFINITY;
    int cur = gid[start];
    for (int n = start; n < end; n++) {
        int g = gid[n];
        if (g != cur) {
            atomicMax(&pooled[cur * 64 + lane], fmap(m));
            cur = g;
            m = -INFINITY;
        }
        m = fmaxf(m, x[(size_t)n * 64 + lane]);
    }
    atomicMax(&pooled[cur * 64 + lane], fmap(m));
}

// ---------- FC head + log_softmax, one block (64 threads) per graph ----------
__global__ __launch_bounds__(64) void fc_kernel(
        const unsigned* __restrict__ pooled,
        const float* __restrict__ Wf1, const float* __restrict__ bf1,
        const float* __restrict__ Wf2, const float* __restrict__ bf2,
        const float* __restrict__ Wf3, const float* __restrict__ bf3,
        float* __restrict__ out) {
    int g = blockIdx.x;
    int c = threadIdx.x;
    __shared__ float x0[64], h1[64], h2[32], h3[10];

    unsigned u = pooled[g * 64 + c];
    x0[c] = (u == NEG_INF_MAPPED) ? 0.f : funmap(u);
    __syncthreads();

    float a = bf1[c];
#pragma unroll 8
    for (int k = 0; k < 64; k++) a = fmaf(Wf1[c * 64 + k], x0[k], a);
    h1[c] = elu_f(a);
    __syncthreads();

    if (c < 32) {
        float a2 = bf2[c];
#pragma unroll 8
        for (int k = 0; k < 64; k++) a2 = fmaf(Wf2[c * 64 + k], h1[k], a2);
        h2[c] = elu_f(a2);
    }
    __syncthreads();

    if (c < 10) {
        float a3 = bf3[c];
#pragma unroll 8
        for (int k = 0; k < 32; k++) a3 = fmaf(Wf3[c * 32 + k], h2[k], a3);
        h3[c] = a3;
    }
    __syncthreads();

    if (c < 10) {
        float mx = h3[0];
#pragma unroll
        for (int j = 1; j < 10; j++) mx = fmaxf(mx, h3[j]);
        float s = 0.f;
#pragma unroll
        for (int j = 0; j < 10; j++) s += expf(h3[j] - mx);
        out[g * 10 + c] = h3[c] - mx - logf(s);
    }
}

// ---------- launch ----------
extern "C" void kernel_launch(void* const* d_in, const int* in_sizes, int n_in,
                              void* d_out, int out_size, void* d_ws, size_t ws_size,
                              hipStream_t stream) {
    const float* atom = (const float*)d_in[0];
    const int* esrc = (const int*)d_in[1];
    const int* edst = (const int*)d_in[2];
    const int* gid  = (const int*)d_in[3];
    const float* Wt1 = (const float*)d_in[4];
    const float* bt1 = (const float*)d_in[5];
    const float* Wp1 = (const float*)d_in[6];
    const float* bp1 = (const float*)d_in[7];
    const float* bng = (const float*)d_in[8];
    const float* bnb = (const float*)d_in[9];
    const float* bnm = (const float*)d_in[10];
    const float* bnv = (const float*)d_in[11];
    const float* Wt2 = (const float*)d_in[12];
    const float* bt2 = (const float*)d_in[13];
    const float* Wp2 = (const float*)d_in[14];
    const float* bp2 = (const float*)d_in[15];
    const float* Wt3 = (const float*)d_in[16];
    const float* bt3 = (const float*)d_in[17];
    const float* Wp3 = (const float*)d_in[18];
    const float* bp3 = (const float*)d_in[19];
    const float* Wf1 = (const float*)d_in[20];
    const float* bf1 = (const float*)d_in[21];
    const float* Wf2 = (const float*)d_in[22];
    const float* bf2 = (const float*)d_in[23];
    const float* Wf3 = (const float*)d_in[24];
    const float* bf3 = (const float*)d_in[25];

    // workspace carve-up
    char* p = (char*)d_ws;
    auto alloc = [&](size_t bytes) -> void* {
        void* r = (void*)p;
        p += (bytes + 255) & ~(size_t)255;
        return r;
    };
    int* offsets    = (int*)alloc(sizeof(int) * (N_NODES + 1));
    int* bcnt       = (int*)alloc(sizeof(int) * NB_BUCKETS);
    int* bbase      = (int*)alloc(sizeof(int) * (NB_BUCKETS + 1));
    int* bcursor    = (int*)alloc(sizeof(int) * NB_BUCKETS);
    unsigned* binned = (unsigned*)alloc(sizeof(unsigned) * N_EDGES);
    int* csr        = (int*)alloc(sizeof(int) * N_EDGES);
    float* Wt1e  = (float*)alloc(sizeof(float) * 32 * 128);
    float* Wq1   = (float*)alloc(sizeof(float) * 32 * 128);
    float* qb1   = (float*)alloc(sizeof(float) * 32);
    float* Wq2   = (float*)alloc(sizeof(float) * 64 * 32);
    float* qb2   = (float*)alloc(sizeof(float) * 64);
    float* Wq3   = (float*)alloc(sizeof(float) * 64 * 64);
    float* qb3   = (float*)alloc(sizeof(float) * 64);
    float* tbuf  = (float*)alloc(sizeof(float) * (size_t)N_NODES * 64);
    __half* qbuf = (__half*)alloc(sizeof(__half) * (size_t)N_NODES * 64);
    float* xbuf  = (float*)alloc(sizeof(float) * (size_t)N_NODES * 64);
    unsigned* pooled = (unsigned*)alloc(sizeof(unsigned) * N_GRAPHS * 64);

    // CSR build (binned, coalesced)
    hipMemsetAsync(bcnt, 0, sizeof(int) * NB_BUCKETS, stream);
    hipMemsetAsync(bcursor, 0, sizeof(int) * NB_BUCKETS, stream);
    prep_kernel<<<16, 256, 0, stream>>>(Wt1, bt1, Wp1, bp1, bng, bnb, bnm, bnv,
                                        Wt2, bt2, Wp2, bp2, Wt3, bt3, Wp3, bp3,
                                        Wt1e, Wq1, qb1, Wq2, qb2, Wq3, qb3);
    bucket_count_kernel<<<512, 256, 0, stream>>>(edst, bcnt, N_EDGES);
    bucket_scan_kernel<<<1, 1024, 0, stream>>>(bcnt, bbase);
    scatter_kernel<<<(N_EDGES + SCAT_CHUNK - 1) / SCAT_CHUNK, 256, 0, stream>>>(
        esrc, edst, bbase, bcursor, binned, N_EDGES);
    bucket_build_kernel<<<NB_BUCKETS, 256, 0, stream>>>(binned, bbase, offsets, csr);

    // layer 1: 128 -> 32 (BN folded)
    transform_kernel<128, 32><<<N_NODES / 32, 256, 0, stream>>>(atom, Wt1e, Wq1, qb1, tbuf, qbuf);
    edgemax_kernel<32><<<N_NODES / 16, 256, 0, stream>>>(tbuf, (const unsigned*)qbuf, offsets, csr, xbuf, N_NODES);

    // layer 2: 32 -> 64
    transform_kernel<32, 64><<<N_NODES / 16, 256, 0, stream>>>(xbuf, Wt2, Wq2, qb2, tbuf, qbuf);
    edgemax_kernel<64><<<N_NODES / 8, 256, 0, stream>>>(tbuf, (const unsigned*)qbuf, offsets, csr, xbuf, N_NODES);

    // layer 3: 64 -> 64
    transform_kernel<64, 64><<<N_NODES / 16, 256, 0, stream>>>(xbuf, Wt3, Wq3, qb3, tbuf, qbuf);
    edgemax_kernel<64><<<N_NODES / 8, 256, 0, stream>>>(tbuf, (const unsigned*)qbuf, offsets, csr, xbuf, N_NODES);

    // graph pooling
    pool_init_kernel<<<(N_GRAPHS * 64 + 255) / 256, 256, 0, stream>>>(pooled, N_GRAPHS * 64);
    {
        int waves = (N_NODES + 63) / 64;
        int blocks = (waves + 3) / 4;  // 4 waves per 256-thread block
        pool_kernel<<<blocks, 256, 0, stream>>>(xbuf, gid, pooled, N_NODES);
    }

    // FC head
    fc_kernel<<<N_GRAPHS, 64, 0, stream>>>(pooled, Wf1, bf1, Wf2, bf2, Wf3, bf3, (float*)d_out);
}

// Round 5
// 228.224 us; speedup vs baseline: 2.0011x; 1.2376x over previous
//
#include <hip/hip_runtime.h>
#include <hip/hip_fp16.h>
#include <math.h>

#define N_NODES 100000
#define N_EDGES 1000000
#define N_GRAPHS 1024
#define BN_EPS 1e-5f

#define BUCKET_NODES 128
#define NB_BUCKETS ((N_NODES + BUCKET_NODES - 1) / BUCKET_NODES)  // 782
#define BUCKET_CAP 3072
#define SCAT_CHUNK 2048

typedef __attribute__((__ext_vector_type__(8))) _Float16 f16x8;
typedef __attribute__((__ext_vector_type__(4))) float f32x4;

// ---------- helpers ----------
static __device__ __forceinline__ float elu_f(float v) {
    return v > 0.f ? v : expm1f(v);
}

// packed fp16 max (2 halves) — gfx950 v_pk_max_f16
static __device__ __forceinline__ unsigned pkmax(unsigned a, unsigned b) {
    unsigned r;
    asm("v_pk_max_f16 %0, %1, %2" : "=v"(r) : "v"(a), "v"(b));
    return r;
}
#define HALF2_NEG_INF 0xFC00FC00u

// monotone float -> uint mapping (order-preserving) for atomicMax on floats
static __device__ __forceinline__ unsigned fmap(float f) {
    unsigned u = __float_as_uint(f);
    return (u & 0x80000000u) ? ~u : (u | 0x80000000u);
}
static __device__ __forceinline__ float funmap(unsigned u) {
    unsigned b = (u & 0x80000000u) ? (u & 0x7FFFFFFFu) : ~u;
    return __uint_as_float(b);
}
#define NEG_INF_MAPPED 0x007FFFFFu  // fmap(-inf)

// ---------- prep: build fragment-order fp16 weight blobs + biases ----------
// Wc[k][c] for layer: c<F -> Wt (scaled), c>=F -> Wq = Wp-Wt (scaled).
// Blob index = ((kf*NCF+cf)*64 + lane)*8 + j, with k = kf*32+(lane>>4)*8+j,
// c = cf*16+(lane&15). This matches the A/B fragment layout of
// v_mfma_f32_16x16x32_f16 so the GEMM kernel loads B with plain dwordx4.
__global__ __launch_bounds__(256) void prep_kernel(
        const float* __restrict__ Wt1, const float* __restrict__ bt1,
        const float* __restrict__ Wp1, const float* __restrict__ bp1,
        const float* __restrict__ gamma, const float* __restrict__ beta,
        const float* __restrict__ mean,  const float* __restrict__ var,
        const float* __restrict__ Wt2, const float* __restrict__ bt2,
        const float* __restrict__ Wp2, const float* __restrict__ bp2,
        const float* __restrict__ Wt3, const float* __restrict__ bt3,
        const float* __restrict__ Wp3, const float* __restrict__ bp3,
        __half* __restrict__ wsz1, float* __restrict__ qb1,
        __half* __restrict__ wsz2, float* __restrict__ qb2,
        __half* __restrict__ wsz3, float* __restrict__ qb3) {
    int idx = blockIdx.x * 256 + threadIdx.x;  // 0..8191

    // layer 1: K=128, F=32, NCF=4 (8192 elems)
    {
        const int K = 128, F = 32, NCF = 4;
        if (idx < K * 2 * F) {
            int frag = idx >> 9, within = idx & 511, lane = within >> 3, j = within & 7;
            int kf = frag / NCF, cf = frag % NCF;
            int k = kf * 32 + (lane >> 4) * 8 + j;
            int c = cf * 16 + (lane & 15);
            float v;
            if (c < F) {
                float s = gamma[c] * rsqrtf(var[c] + BN_EPS);
                v = Wt1[c * K + k] * s;
            } else {
                int cc = c - F;
                float s = gamma[cc] * rsqrtf(var[cc] + BN_EPS);
                v = (Wp1[cc * K + k] - Wt1[cc * K + k]) * s;
            }
            wsz1[idx] = __float2half(v);
        }
        if (idx < F) {
            float s = gamma[idx] * rsqrtf(var[idx] + BN_EPS);
            qb1[idx] = (bt1[idx] + bp1[idx]) * s + beta[idx] - mean[idx] * s;
        }
    }
    // layer 2: K=32, F=64, NCF=8 (4096 elems)
    {
        const int K = 32, F = 64, NCF = 8;
        if (idx < K * 2 * F) {
            int frag = idx >> 9, within = idx & 511, lane = within >> 3, j = within & 7;
            int kf = frag / NCF, cf = frag % NCF;
            int k = kf * 32 + (lane >> 4) * 8 + j;
            int c = cf * 16 + (lane & 15);
            float v = (c < F) ? Wt2[c * K + k]
                              : (Wp2[(c - F) * K + k] - Wt2[(c - F) * K + k]);
            wsz2[idx] = __float2half(v);
        }
        if (idx < F) qb2[idx] = bt2[idx] + bp2[idx];
    }
    // layer 3: K=64, F=64, NCF=8 (8192 elems)
    {
        const int K = 64, F = 64, NCF = 8;
        if (idx < K * 2 * F) {
            int frag = idx >> 9, within = idx & 511, lane = within >> 3, j = within & 7;
            int kf = frag / NCF, cf = frag % NCF;
            int k = kf * 32 + (lane >> 4) * 8 + j;
            int c = cf * 16 + (lane & 15);
            float v = (c < F) ? Wt3[c * K + k]
                              : (Wp3[(c - F) * K + k] - Wt3[(c - F) * K + k]);
            wsz3[idx] = __float2half(v);
        }
        if (idx < F) qb3[idx] = bt3[idx] + bp3[idx];
    }
}

// ---------- binned CSR build ----------
__global__ __launch_bounds__(256) void bucket_count_kernel(const int* __restrict__ edst,
                                                           int* __restrict__ bcnt, int E) {
    __shared__ int h[NB_BUCKETS];
    for (int i = threadIdx.x; i < NB_BUCKETS; i += 256) h[i] = 0;
    __syncthreads();
    int stride = gridDim.x * 256;
    for (int i = blockIdx.x * 256 + threadIdx.x; i < E; i += stride)
        atomicAdd(&h[edst[i] >> 7], 1);
    __syncthreads();
    for (int i = threadIdx.x; i < NB_BUCKETS; i += 256) {
        int c = h[i];
        if (c) atomicAdd(&bcnt[i], c);
    }
}

__global__ __launch_bounds__(1024) void bucket_scan_kernel(const int* __restrict__ bcnt,
                                                           int* __restrict__ base) {
    __shared__ int s[1024];
    int t = threadIdx.x;
    int v = (t < NB_BUCKETS) ? bcnt[t] : 0;
    s[t] = v;
    __syncthreads();
    for (int off = 1; off < 1024; off <<= 1) {
        int u = (t >= off) ? s[t - off] : 0;
        __syncthreads();
        s[t] += u;
        __syncthreads();
    }
    if (t < NB_BUCKETS) base[t + 1] = s[t];
    if (t == 0) base[0] = 0;
}

__global__ __launch_bounds__(256) void scatter_kernel(const int* __restrict__ esrc,
                                                      const int* __restrict__ edst,
                                                      const int* __restrict__ base,
                                                      int* __restrict__ cursor,
                                                      unsigned* __restrict__ binned, int E) {
    __shared__ int hist[NB_BUCKETS];
    __shared__ int lbase[NB_BUCKETS];
    __shared__ unsigned pk[SCAT_CHUNK];
    __shared__ unsigned short bk[SCAT_CHUNK];
    int begE = blockIdx.x * SCAT_CHUNK;
    int endE = min(begE + SCAT_CHUNK, E);
    int n = endE - begE;
    for (int i = threadIdx.x; i < NB_BUCKETS; i += 256) hist[i] = 0;
    __syncthreads();
    for (int i = threadIdx.x; i < n; i += 256) {
        int d = edst[begE + i];
        int s = esrc[begE + i];
        int b = d >> 7;
        pk[i] = ((unsigned)s << 7) | (unsigned)(d & 127);
        bk[i] = (unsigned short)b;
        atomicAdd(&hist[b], 1);
    }
    __syncthreads();
    for (int i = threadIdx.x; i < NB_BUCKETS; i += 256) {
        int c = hist[i];
        lbase[i] = c ? (base[i] + atomicAdd(&cursor[i], c)) : 0;
        hist[i] = 0;  // reuse as local cursor
    }
    __syncthreads();
    for (int i = threadIdx.x; i < n; i += 256) {
        int b = bk[i];
        int pos = lbase[b] + atomicAdd(&hist[b], 1);
        binned[pos] = pk[i];
    }
}

__global__ __launch_bounds__(256) void bucket_build_kernel(const unsigned* __restrict__ binned,
                                                           const int* __restrict__ base,
                                                           int* __restrict__ offsets,
                                                           int* __restrict__ csr) {
    __shared__ unsigned stage[BUCKET_CAP];
    __shared__ int srcLDS[BUCKET_CAP];
    __shared__ int cnt[BUCKET_NODES];
    __shared__ int sc[BUCKET_NODES];
    __shared__ int loff[BUCKET_NODES];

    int b = blockIdx.x;
    int ebeg = base[b], eend = base[b + 1];
    int ne = eend - ebeg;
    int tid = threadIdx.x;

    if (tid < BUCKET_NODES) cnt[tid] = 0;
    __syncthreads();
    for (int i = tid; i < ne; i += 256) {
        unsigned e = binned[ebeg + i];
        stage[i] = e;
        atomicAdd(&cnt[e & 127], 1);
    }
    __syncthreads();
    int v = (tid < BUCKET_NODES) ? cnt[tid] : 0;
    if (tid < BUCKET_NODES) sc[tid] = v;
    __syncthreads();
    for (int off = 1; off < BUCKET_NODES; off <<= 1) {
        int u = (tid < BUCKET_NODES && tid >= off) ? sc[tid - off] : 0;
        __syncthreads();
        if (tid < BUCKET_NODES) sc[tid] += u;
        __syncthreads();
    }
    if (tid < BUCKET_NODES) {
        loff[tid] = sc[tid] - v;
        cnt[tid] = 0;
    }
    __syncthreads();
    int gnode = b * BUCKET_NODES + tid;
    if (tid < BUCKET_NODES && gnode < N_NODES) offsets[gnode] = ebeg + loff[tid];
    if (b == gridDim.x - 1 && tid == 0) offsets[N_NODES] = eend;
    for (int i = tid; i < ne; i += 256) {
        unsigned e = stage[i];
        int ln = e & 127;
        int slot = loff[ln] + atomicAdd(&cnt[ln], 1);
        srcLDS[slot] = (int)(e >> 7);
    }
    __syncthreads();
    for (int i = tid; i < ne; i += 256) csr[ebeg + i] = srcLDS[i];
}

// ---------- A-fragment loaders ----------
template <int K>
static __device__ __forceinline__ f16x8 load_afrag(const __half* __restrict__ x,
                                                   size_t rowIdx, int kOff) {
    return *reinterpret_cast<const f16x8*>(x + rowIdx * K + kOff);
}
template <int K>
static __device__ __forceinline__ f16x8 load_afrag(const float* __restrict__ x,
                                                   size_t rowIdx, int kOff) {
    const float* xr = x + rowIdx * K + kOff;
    float4 a0 = *reinterpret_cast<const float4*>(xr);
    float4 a1 = *reinterpret_cast<const float4*>(xr + 4);
    f16x8 a;
    a[0] = (_Float16)a0.x; a[1] = (_Float16)a0.y; a[2] = (_Float16)a0.z; a[3] = (_Float16)a0.w;
    a[4] = (_Float16)a1.x; a[5] = (_Float16)a1.y; a[6] = (_Float16)a1.z; a[7] = (_Float16)a1.w;
    return a;
}

// ---------- MFMA transform: D[100000 x 2F] = x[100000 x K] @ Wc[K x 2F] ----------
// cols 0..F-1 -> t (fp32), cols F..2F-1 -> q + qbias (fp16).
// One wave per 16-node tile, grid-stride over tiles. B held in registers.
template <int K, int F, typename IT>
__global__ __launch_bounds__(256) void transform_mfma(
        const IT* __restrict__ x, const __half* __restrict__ wsz,
        const float* __restrict__ qb,
        float* __restrict__ t, __half* __restrict__ q) {
    constexpr int NKF = K / 32;
    constexpr int NCF = (2 * F) / 16;
    constexpr int NTILES = N_NODES / 16;  // 6250

    int lane = threadIdx.x & 63;
    int wid = blockIdx.x * 4 + (threadIdx.x >> 6);
    int nWaves = gridDim.x * 4;

    // load B fragments (shared by all tiles this wave processes)
    f16x8 bfrag[NKF][NCF];
#pragma unroll
    for (int kf = 0; kf < NKF; kf++)
#pragma unroll
        for (int cf = 0; cf < NCF; cf++)
            bfrag[kf][cf] = *reinterpret_cast<const f16x8*>(
                wsz + ((size_t)(kf * NCF + cf) * 64 + lane) * 8);

    int row = lane & 15;       // A row (m) within tile
    int kq = lane >> 4;        // k-quad selector
    int col = lane & 15;       // D col within cfrag
    int rbase = (lane >> 4) * 4;  // D row base within tile

    for (int tile = wid; tile < NTILES; tile += nWaves) {
        size_t nodeBase = (size_t)tile * 16;

        f32x4 acc[NCF];
#pragma unroll
        for (int cf = 0; cf < NCF; cf++) acc[cf] = (f32x4){0.f, 0.f, 0.f, 0.f};

#pragma unroll
        for (int kf = 0; kf < NKF; kf++) {
            f16x8 a = load_afrag<K>(x, nodeBase + row, kf * 32 + kq * 8);
#pragma unroll
            for (int cf = 0; cf < NCF; cf++)
                acc[cf] = __builtin_amdgcn_mfma_f32_16x16x32_f16(a, bfrag[kf][cf], acc[cf], 0, 0, 0);
        }

#pragma unroll
        for (int cf = 0; cf < NCF; cf++) {
            int c = cf * 16 + col;
            if (c < F) {
#pragma unroll
                for (int r = 0; r < 4; r++) {
                    size_t node = nodeBase + rbase + r;
                    t[node * F + c] = acc[cf][r];
                }
            } else {
                float qbv = qb[c - F];
#pragma unroll
                for (int r = 0; r < 4; r++) {
                    size_t node = nodeBase + rbase + r;
                    q[node * F + (c - F)] = __float2half(acc[cf][r] + qbv);
                }
            }
        }
    }
}

// ---------- edge max + combine + ELU (fp16 gather, packed max, 4x unroll) ----------
// out (fp16) = indeg>0 ? elu(t + max q[src]) : 0
template <int F>
__global__ __launch_bounds__(256) void edgemax_kernel(
        const float* __restrict__ t, const unsigned* __restrict__ q,  // q: half2 rows [N][F/2]
        const int* __restrict__ offsets, const int* __restrict__ csr,
        __half* __restrict__ out, int N) {
    constexpr int NPG = F / 2;
    constexpr int G = 256 / NPG;
    int g = threadIdx.x / NPG;
    int cp = threadIdx.x % NPG;
    int nd = blockIdx.x * G + g;
    if (nd >= N) return;
    int beg = offsets[nd], end = offsets[nd + 1];

    unsigned m0 = HALF2_NEG_INF, m1 = HALF2_NEG_INF;
    int i = beg;
    for (; i + 3 < end; i += 4) {
        int s0 = csr[i], s1 = csr[i + 1], s2 = csr[i + 2], s3 = csr[i + 3];
        unsigned v0 = q[(size_t)s0 * NPG + cp];
        unsigned v1 = q[(size_t)s1 * NPG + cp];
        unsigned v2 = q[(size_t)s2 * NPG + cp];
        unsigned v3 = q[(size_t)s3 * NPG + cp];
        m0 = pkmax(m0, pkmax(v0, v1));
        m1 = pkmax(m1, pkmax(v2, v3));
    }
    for (; i < end; i++) {
        m0 = pkmax(m0, q[(size_t)csr[i] * NPG + cp]);
    }
    unsigned m = pkmax(m0, m1);

    float2 r;
    if (beg < end) {
        __half2 mh = __builtin_bit_cast(__half2, m);
        float2 mf = __half22float2(mh);
        float2 tv = *reinterpret_cast<const float2*>(t + (size_t)nd * F + 2 * cp);
        r.x = elu_f(tv.x + mf.x);
        r.y = elu_f(tv.y + mf.y);
    } else {
        r.x = 0.f; r.y = 0.f;
    }
    *reinterpret_cast<__half2*>(out + (size_t)nd * F + 2 * cp) = __floats2half2_rn(r.x, r.y);
}

// ---------- graph max pooling (fp16 input) ----------
__global__ void pool_init_kernel(unsigned* __restrict__ p, int n) {
    int i = blockIdx.x * blockDim.x + threadIdx.x;
    if (i < n) p[i] = NEG_INF_MAPPED;
}

__global__ void pool_kernel(const __half* __restrict__ x, const int* __restrict__ gid,
                            unsigned* __restrict__ pooled, int N) {
    const int CHUNK = 64;
    int wave = (blockIdx.x * blockDim.x + threadIdx.x) >> 6;
    int lane = threadIdx.x & 63;
    int start = wave * CHUNK;
    if (start >= N) return;
    int end = min(start + CHUNK, N);
    float m = -INFINITY;
    int cur = gid[start];
    for (int n = start; n < end; n++) {
        int g = gid[n];
        if (g != cur) {
            atomicMax(&pooled[cur * 64 + lane], fmap(m));
            cur = g;
            m = -INFINITY;
        }
        m = fmaxf(m, __half2float(x[(size_t)n * 64 + lane]));
    }
    atomicMax(&pooled[cur * 64 + lane], fmap(m));
}

// ---------- FC head + log_softmax, one block (64 threads) per graph ----------
__global__ __launch_bounds__(64) void fc_kernel(
        const unsigned* __restrict__ pooled,
        const float* __restrict__ Wf1, const float* __restrict__ bf1,
        const float* __restrict__ Wf2, const float* __restrict__ bf2,
        const float* __restrict__ Wf3, const float* __restrict__ bf3,
        float* __restrict__ out) {
    int g = blockIdx.x;
    int c = threadIdx.x;
    __shared__ float x0[64], h1[64], h2[32], h3[10];

    unsigned u = pooled[g * 64 + c];
    x0[c] = (u == NEG_INF_MAPPED) ? 0.f : funmap(u);
    __syncthreads();

    float a = bf1[c];
#pragma unroll 8
    for (int k = 0; k < 64; k++) a = fmaf(Wf1[c * 64 + k], x0[k], a);
    h1[c] = elu_f(a);
    __syncthreads();

    if (c < 32) {
        float a2 = bf2[c];
#pragma unroll 8
        for (int k = 0; k < 64; k++) a2 = fmaf(Wf2[c * 64 + k], h1[k], a2);
        h2[c] = elu_f(a2);
    }
    __syncthreads();

    if (c < 10) {
        float a3 = bf3[c];
#pragma unroll 8
        for (int k = 0; k < 32; k++) a3 = fmaf(Wf3[c * 32 + k], h2[k], a3);
        h3[c] = a3;
    }
    __syncthreads();

    if (c < 10) {
        float mx = h3[0];
#pragma unroll
        for (int j = 1; j < 10; j++) mx = fmaxf(mx, h3[j]);
        float s = 0.f;
#pragma unroll
        for (int j = 0; j < 10; j++) s += expf(h3[j] - mx);
        out[g * 10 + c] = h3[c] - mx - logf(s);
    }
}

// ---------- launch ----------
extern "C" void kernel_launch(void* const* d_in, const int* in_sizes, int n_in,
                              void* d_out, int out_size, void* d_ws, size_t ws_size,
                              hipStream_t stream) {
    const float* atom = (const float*)d_in[0];
    const int* esrc = (const int*)d_in[1];
    const int* edst = (const int*)d_in[2];
    const int* gid  = (const int*)d_in[3];
    const float* Wt1 = (const float*)d_in[4];
    const float* bt1 = (const float*)d_in[5];
    const float* Wp1 = (const float*)d_in[6];
    const float* bp1 = (const float*)d_in[7];
    const float* bng = (const float*)d_in[8];
    const float* bnb = (const float*)d_in[9];
    const float* bnm = (const float*)d_in[10];
    const float* bnv = (const float*)d_in[11];
    const float* Wt2 = (const float*)d_in[12];
    const float* bt2 = (const float*)d_in[13];
    const float* Wp2 = (const float*)d_in[14];
    const float* bp2 = (const float*)d_in[15];
    const float* Wt3 = (const float*)d_in[16];
    const float* bt3 = (const float*)d_in[17];
    const float* Wp3 = (const float*)d_in[18];
    const float* bp3 = (const float*)d_in[19];
    const float* Wf1 = (const float*)d_in[20];
    const float* bf1 = (const float*)d_in[21];
    const float* Wf2 = (const float*)d_in[22];
    const float* bf2 = (const float*)d_in[23];
    const float* Wf3 = (const float*)d_in[24];
    const float* bf3 = (const float*)d_in[25];

    // workspace carve-up
    char* p = (char*)d_ws;
    auto alloc = [&](size_t bytes) -> void* {
        void* r = (void*)p;
        p += (bytes + 255) & ~(size_t)255;
        return r;
    };
    int* offsets     = (int*)alloc(sizeof(int) * (N_NODES + 1));
    int* bcnt        = (int*)alloc(sizeof(int) * NB_BUCKETS);
    int* bbase       = (int*)alloc(sizeof(int) * (NB_BUCKETS + 1));
    int* bcursor     = (int*)alloc(sizeof(int) * NB_BUCKETS);
    unsigned* binned = (unsigned*)alloc(sizeof(unsigned) * N_EDGES);
    int* csr         = (int*)alloc(sizeof(int) * N_EDGES);
    __half* wsz1 = (__half*)alloc(sizeof(__half) * 128 * 64);
    __half* wsz2 = (__half*)alloc(sizeof(__half) * 32 * 128);
    __half* wsz3 = (__half*)alloc(sizeof(__half) * 64 * 128);
    float* qb1   = (float*)alloc(sizeof(float) * 32);
    float* qb2   = (float*)alloc(sizeof(float) * 64);
    float* qb3   = (float*)alloc(sizeof(float) * 64);
    float* tbuf  = (float*)alloc(sizeof(float) * (size_t)N_NODES * 64);
    __half* qbuf = (__half*)alloc(sizeof(__half) * (size_t)N_NODES * 64);
    __half* xh   = (__half*)alloc(sizeof(__half) * (size_t)N_NODES * 64);
    unsigned* pooled = (unsigned*)alloc(sizeof(unsigned) * N_GRAPHS * 64);

    // CSR build (binned, coalesced)
    hipMemsetAsync(bcnt, 0, sizeof(int) * NB_BUCKETS, stream);
    hipMemsetAsync(bcursor, 0, sizeof(int) * NB_BUCKETS, stream);
    prep_kernel<<<32, 256, 0, stream>>>(Wt1, bt1, Wp1, bp1, bng, bnb, bnm, bnv,
                                        Wt2, bt2, Wp2, bp2, Wt3, bt3, Wp3, bp3,
                                        wsz1, qb1, wsz2, qb2, wsz3, qb3);
    bucket_count_kernel<<<512, 256, 0, stream>>>(edst, bcnt, N_EDGES);
    bucket_scan_kernel<<<1, 1024, 0, stream>>>(bcnt, bbase);
    scatter_kernel<<<(N_EDGES + SCAT_CHUNK - 1) / SCAT_CHUNK, 256, 0, stream>>>(
        esrc, edst, bbase, bcursor, binned, N_EDGES);
    bucket_build_kernel<<<NB_BUCKETS, 256, 0, stream>>>(binned, bbase, offsets, csr);

    // layer 1: 128 -> 32 (BN folded), fp32 input
    transform_mfma<128, 32, float><<<1024, 256, 0, stream>>>(atom, wsz1, qb1, tbuf, qbuf);
    edgemax_kernel<32><<<N_NODES / 16, 256, 0, stream>>>(tbuf, (const unsigned*)qbuf, offsets, csr, xh, N_NODES);

    // layer 2: 32 -> 64, fp16 input
    transform_mfma<32, 64, __half><<<1024, 256, 0, stream>>>(xh, wsz2, qb2, tbuf, qbuf);
    edgemax_kernel<64><<<N_NODES / 8, 256, 0, stream>>>(tbuf, (const unsigned*)qbuf, offsets, csr, xh, N_NODES);

    // layer 3: 64 -> 64, fp16 input
    transform_mfma<64, 64, __half><<<1024, 256, 0, stream>>>(xh, wsz3, qb3, tbuf, qbuf);
    edgemax_kernel<64><<<N_NODES / 8, 256, 0, stream>>>(tbuf, (const unsigned*)qbuf, offsets, csr, xh, N_NODES);

    // graph pooling
    pool_init_kernel<<<(N_GRAPHS * 64 + 255) / 256, 256, 0, stream>>>(pooled, N_GRAPHS * 64);
    {
        int waves = (N_NODES + 63) / 64;
        int blocks = (waves + 3) / 4;
        pool_kernel<<<blocks, 256, 0, stream>>>(xh, gid, pooled, N_NODES);
    }

    // FC head
    fc_kernel<<<N_GRAPHS, 64, 0, stream>>>(pooled, Wf1, bf1, Wf2, bf2, Wf3, bf3, (float*)d_out);
}

// Round 6
// 179.756 us; speedup vs baseline: 2.5407x; 1.2696x over previous
//
#include <hip/hip_runtime.h>
#include <hip/hip_fp16.h>
#include <math.h>

#define N_NODES 100000
#define N_EDGES 1000000
#define N_GRAPHS 1024
#define BN_EPS 1e-5f

#define BUCKET_NODES 128
#define NB_BUCKETS ((N_NODES + BUCKET_NODES - 1) / BUCKET_NODES)  // 782
#define BUCKET_PAD 2048   // fixed per-bucket slot; counts ~Poisson(1280), >20 sigma margin
#define BUCKET_CAP 3072
#define SCAT_CHUNK 2048

typedef __attribute__((__ext_vector_type__(8))) _Float16 f16x8;
typedef __attribute__((__ext_vector_type__(4))) float f32x4;

// ---------- helpers ----------
static __device__ __forceinline__ float elu_f(float v) {
    return v > 0.f ? v : expm1f(v);
}

// packed fp16 max (2 halves) — gfx950 v_pk_max_f16
static __device__ __forceinline__ unsigned pkmax(unsigned a, unsigned b) {
    unsigned r;
    asm("v_pk_max_f16 %0, %1, %2" : "=v"(r) : "v"(a), "v"(b));
    return r;
}
#define HALF2_NEG_INF 0xFC00FC00u

static __device__ __forceinline__ uint4 pkmax4(uint4 a, uint4 b) {
    uint4 r;
    r.x = pkmax(a.x, b.x);
    r.y = pkmax(a.y, b.y);
    r.z = pkmax(a.z, b.z);
    r.w = pkmax(a.w, b.w);
    return r;
}

// monotone float -> uint mapping (order-preserving) for atomicMax on floats
static __device__ __forceinline__ unsigned fmap(float f) {
    unsigned u = __float_as_uint(f);
    return (u & 0x80000000u) ? ~u : (u | 0x80000000u);
}
static __device__ __forceinline__ float funmap(unsigned u) {
    unsigned b = (u & 0x80000000u) ? (u & 0x7FFFFFFFu) : ~u;
    return __uint_as_float(b);
}
#define NEG_INF_MAPPED 0x007FFFFFu  // fmap(-inf)

// ---------- prep: fragment-order fp16 weight blobs + biases + cursor zero ----------
__global__ __launch_bounds__(256) void prep_kernel(
        const float* __restrict__ Wt1, const float* __restrict__ bt1,
        const float* __restrict__ Wp1, const float* __restrict__ bp1,
        const float* __restrict__ gamma, const float* __restrict__ beta,
        const float* __restrict__ mean,  const float* __restrict__ var,
        const float* __restrict__ Wt2, const float* __restrict__ bt2,
        const float* __restrict__ Wp2, const float* __restrict__ bp2,
        const float* __restrict__ Wt3, const float* __restrict__ bt3,
        const float* __restrict__ Wp3, const float* __restrict__ bp3,
        __half* __restrict__ wsz1, float* __restrict__ qb1,
        __half* __restrict__ wsz2, float* __restrict__ qb2,
        __half* __restrict__ wsz3, float* __restrict__ qb3,
        int* __restrict__ cursor) {
    int idx = blockIdx.x * 256 + threadIdx.x;  // 0..8191

    if (idx < NB_BUCKETS) cursor[idx] = 0;

    // layer 1: K=128, F=32, NCF=4 (8192 elems)
    {
        const int K = 128, F = 32, NCF = 4;
        if (idx < K * 2 * F) {
            int frag = idx >> 9, within = idx & 511, lane = within >> 3, j = within & 7;
            int kf = frag / NCF, cf = frag % NCF;
            int k = kf * 32 + (lane >> 4) * 8 + j;
            int c = cf * 16 + (lane & 15);
            float v;
            if (c < F) {
                float s = gamma[c] * rsqrtf(var[c] + BN_EPS);
                v = Wt1[c * K + k] * s;
            } else {
                int cc = c - F;
                float s = gamma[cc] * rsqrtf(var[cc] + BN_EPS);
                v = (Wp1[cc * K + k] - Wt1[cc * K + k]) * s;
            }
            wsz1[idx] = __float2half(v);
        }
        if (idx < F) {
            float s = gamma[idx] * rsqrtf(var[idx] + BN_EPS);
            qb1[idx] = (bt1[idx] + bp1[idx]) * s + beta[idx] - mean[idx] * s;
        }
    }
    // layer 2: K=32, F=64, NCF=8 (4096 elems)
    {
        const int K = 32, F = 64, NCF = 8;
        if (idx < K * 2 * F) {
            int frag = idx >> 9, within = idx & 511, lane = within >> 3, j = within & 7;
            int kf = frag / NCF, cf = frag % NCF;
            int k = kf * 32 + (lane >> 4) * 8 + j;
            int c = cf * 16 + (lane & 15);
            float v = (c < F) ? Wt2[c * K + k]
                              : (Wp2[(c - F) * K + k] - Wt2[(c - F) * K + k]);
            wsz2[idx] = __float2half(v);
        }
        if (idx < F) qb2[idx] = bt2[idx] + bp2[idx];
    }
    // layer 3: K=64, F=64, NCF=8 (8192 elems)
    {
        const int K = 64, F = 64, NCF = 8;
        if (idx < K * 2 * F) {
            int frag = idx >> 9, within = idx & 511, lane = within >> 3, j = within & 7;
            int kf = frag / NCF, cf = frag % NCF;
            int k = kf * 32 + (lane >> 4) * 8 + j;
            int c = cf * 16 + (lane & 15);
            float v = (c < F) ? Wt3[c * K + k]
                              : (Wp3[(c - F) * K + k] - Wt3[(c - F) * K + k]);
            wsz3[idx] = __float2half(v);
        }
        if (idx < F) qb3[idx] = bt3[idx] + bp3[idx];
    }
}

// ---------- binned CSR build (padded buckets, no global scan) ----------
// bucket = dst >> 7. Packed edge: (src << 7) | (dst & 127).
__global__ __launch_bounds__(256) void scatter_kernel(const int* __restrict__ esrc,
                                                      const int* __restrict__ edst,
                                                      int* __restrict__ cursor,
                                                      unsigned* __restrict__ binned, int E) {
    __shared__ int hist[NB_BUCKETS];
    __shared__ int lbase[NB_BUCKETS];
    __shared__ unsigned pk[SCAT_CHUNK];
    __shared__ unsigned short bk[SCAT_CHUNK];
    int begE = blockIdx.x * SCAT_CHUNK;
    int endE = min(begE + SCAT_CHUNK, E);
    int n = endE - begE;
    for (int i = threadIdx.x; i < NB_BUCKETS; i += 256) hist[i] = 0;
    __syncthreads();
    for (int i = threadIdx.x; i < n; i += 256) {
        int d = edst[begE + i];
        int s = esrc[begE + i];
        int b = d >> 7;
        pk[i] = ((unsigned)s << 7) | (unsigned)(d & 127);
        bk[i] = (unsigned short)b;
        atomicAdd(&hist[b], 1);
    }
    __syncthreads();
    for (int i = threadIdx.x; i < NB_BUCKETS; i += 256) {
        int c = hist[i];
        lbase[i] = c ? (i * BUCKET_PAD + atomicAdd(&cursor[i], c)) : 0;
        hist[i] = 0;  // reuse as local cursor
    }
    __syncthreads();
    for (int i = threadIdx.x; i < n; i += 256) {
        int b = bk[i];
        int pos = lbase[b] + atomicAdd(&hist[b], 1);
        binned[pos] = pk[i];
    }
}

// one block per bucket: LDS-local CSR build, coalesced csr/beg/end writes.
__global__ __launch_bounds__(256) void bucket_build_kernel(const unsigned* __restrict__ binned,
                                                           const int* __restrict__ bcount,
                                                           int* __restrict__ begs,
                                                           int* __restrict__ ends,
                                                           int* __restrict__ csr) {
    __shared__ unsigned stage[BUCKET_CAP];
    __shared__ int srcLDS[BUCKET_CAP];
    __shared__ int cnt[BUCKET_NODES];
    __shared__ int sc[BUCKET_NODES];
    __shared__ int loff[BUCKET_NODES];

    int b = blockIdx.x;
    int ebeg = b * BUCKET_PAD;
    int ne = min(bcount[b], BUCKET_CAP);
    int tid = threadIdx.x;

    if (tid < BUCKET_NODES) cnt[tid] = 0;
    __syncthreads();
    for (int i = tid; i < ne; i += 256) {
        unsigned e = binned[ebeg + i];
        stage[i] = e;
        atomicAdd(&cnt[e & 127], 1);
    }
    __syncthreads();
    int v = (tid < BUCKET_NODES) ? cnt[tid] : 0;
    if (tid < BUCKET_NODES) sc[tid] = v;
    __syncthreads();
    for (int off = 1; off < BUCKET_NODES; off <<= 1) {
        int u = (tid < BUCKET_NODES && tid >= off) ? sc[tid - off] : 0;
        __syncthreads();
        if (tid < BUCKET_NODES) sc[tid] += u;
        __syncthreads();
    }
    if (tid < BUCKET_NODES) {
        loff[tid] = sc[tid] - v;
        cnt[tid] = 0;
    }
    __syncthreads();
    int gnode = b * BUCKET_NODES + tid;
    if (tid < BUCKET_NODES && gnode < N_NODES) {
        begs[gnode] = ebeg + loff[tid];
        ends[gnode] = ebeg + loff[tid] + v;
    }
    for (int i = tid; i < ne; i += 256) {
        unsigned e = stage[i];
        int ln = e & 127;
        int slot = loff[ln] + atomicAdd(&cnt[ln], 1);
        srcLDS[slot] = (int)(e >> 7);
    }
    __syncthreads();
    for (int i = tid; i < ne; i += 256) csr[ebeg + i] = srcLDS[i];
}

// ---------- A-fragment loaders ----------
template <int K>
static __device__ __forceinline__ f16x8 load_afrag(const __half* __restrict__ x,
                                                   size_t rowIdx, int kOff) {
    return *reinterpret_cast<const f16x8*>(x + rowIdx * K + kOff);
}
template <int K>
static __device__ __forceinline__ f16x8 load_afrag(const float* __restrict__ x,
                                                   size_t rowIdx, int kOff) {
    const float* xr = x + rowIdx * K + kOff;
    float4 a0 = *reinterpret_cast<const float4*>(xr);
    float4 a1 = *reinterpret_cast<const float4*>(xr + 4);
    f16x8 a;
    a[0] = (_Float16)a0.x; a[1] = (_Float16)a0.y; a[2] = (_Float16)a0.z; a[3] = (_Float16)a0.w;
    a[4] = (_Float16)a1.x; a[5] = (_Float16)a1.y; a[6] = (_Float16)a1.z; a[7] = (_Float16)a1.w;
    return a;
}

// ---------- MFMA transform: [100000 x K] @ [K x 2F] -> t (fp16), q+qbias (fp16) ----------
template <int K, int F, typename IT>
__global__ __launch_bounds__(256) void transform_mfma(
        const IT* __restrict__ x, const __half* __restrict__ wsz,
        const float* __restrict__ qb,
        __half* __restrict__ t, __half* __restrict__ q) {
    constexpr int NKF = K / 32;
    constexpr int NCF = (2 * F) / 16;
    constexpr int NTILES = N_NODES / 16;  // 6250

    int lane = threadIdx.x & 63;
    int wid = blockIdx.x * 4 + (threadIdx.x >> 6);
    int nWaves = gridDim.x * 4;

    f16x8 bfrag[NKF][NCF];
#pragma unroll
    for (int kf = 0; kf < NKF; kf++)
#pragma unroll
        for (int cf = 0; cf < NCF; cf++)
            bfrag[kf][cf] = *reinterpret_cast<const f16x8*>(
                wsz + ((size_t)(kf * NCF + cf) * 64 + lane) * 8);

    int row = lane & 15;
    int kq = lane >> 4;
    int col = lane & 15;
    int rbase = (lane >> 4) * 4;

    for (int tile = wid; tile < NTILES; tile += nWaves) {
        size_t nodeBase = (size_t)tile * 16;

        f32x4 acc[NCF];
#pragma unroll
        for (int cf = 0; cf < NCF; cf++) acc[cf] = (f32x4){0.f, 0.f, 0.f, 0.f};

#pragma unroll
        for (int kf = 0; kf < NKF; kf++) {
            f16x8 a = load_afrag<K>(x, nodeBase + row, kf * 32 + kq * 8);
#pragma unroll
            for (int cf = 0; cf < NCF; cf++)
                acc[cf] = __builtin_amdgcn_mfma_f32_16x16x32_f16(a, bfrag[kf][cf], acc[cf], 0, 0, 0);
        }

#pragma unroll
        for (int cf = 0; cf < NCF; cf++) {
            int c = cf * 16 + col;
            if (c < F) {
#pragma unroll
                for (int r = 0; r < 4; r++) {
                    size_t node = nodeBase + rbase + r;
                    t[node * F + c] = __float2half(acc[cf][r]);
                }
            } else {
                float qbv = qb[c - F];
#pragma unroll
                for (int r = 0; r < 4; r++) {
                    size_t node = nodeBase + rbase + r;
                    q[node * F + (c - F)] = __float2half(acc[cf][r] + qbv);
                }
            }
        }
    }
}

// ---------- edge max + combine + ELU (uint4 = 8-channel gathers) ----------
// out[d][c] = indeg(d)>0 ? elu(t[d][c] + max_{s in in(d)} q[s][c]) : 0
template <int F>
__global__ __launch_bounds__(256) void edgemax_kernel(
        const uint4* __restrict__ t16, const uint4* __restrict__ q16,  // [N][F/8]
        const int* __restrict__ begs, const int* __restrict__ ends,
        const int* __restrict__ csr,
        uint4* __restrict__ out, int N) {
    constexpr int NPG = F / 8;      // threads per node (8 channels each)
    constexpr int G = 256 / NPG;    // nodes per block
    int g = threadIdx.x / NPG;
    int cp = threadIdx.x % NPG;
    int nd = blockIdx.x * G + g;
    if (nd >= N) return;
    int beg = begs[nd], end = ends[nd];

    uint4 m0 = {HALF2_NEG_INF, HALF2_NEG_INF, HALF2_NEG_INF, HALF2_NEG_INF};
    uint4 m1 = m0;
    int i = beg;
    for (; i + 1 < end; i += 2) {
        int s0 = csr[i], s1 = csr[i + 1];
        uint4 v0 = q16[(size_t)s0 * NPG + cp];
        uint4 v1 = q16[(size_t)s1 * NPG + cp];
        m0 = pkmax4(m0, v0);
        m1 = pkmax4(m1, v1);
    }
    if (i < end) {
        m0 = pkmax4(m0, q16[(size_t)csr[i] * NPG + cp]);
    }
    uint4 m = pkmax4(m0, m1);

    uint4 res;
    if (beg < end) {
        uint4 tv = t16[(size_t)nd * NPG + cp];
        unsigned* mp = &m.x;
        unsigned* tp = &tv.x;
        unsigned* rp = &res.x;
#pragma unroll
        for (int w = 0; w < 4; w++) {
            float2 mf = __half22float2(__builtin_bit_cast(__half2, mp[w]));
            float2 tf = __half22float2(__builtin_bit_cast(__half2, tp[w]));
            float rx = elu_f(tf.x + mf.x);
            float ry = elu_f(tf.y + mf.y);
            rp[w] = __builtin_bit_cast(unsigned, __floats2half2_rn(rx, ry));
        }
    } else {
        res = (uint4){0u, 0u, 0u, 0u};
    }
    out[(size_t)nd * NPG + cp] = res;
}

// ---------- graph max pooling (fp16 input) ----------
__global__ void pool_init_kernel(unsigned* __restrict__ p, int n) {
    int i = blockIdx.x * blockDim.x + threadIdx.x;
    if (i < n) p[i] = NEG_INF_MAPPED;
}

__global__ void pool_kernel(const __half* __restrict__ x, const int* __restrict__ gid,
                            unsigned* __restrict__ pooled, int N) {
    const int CHUNK = 64;
    int wave = (blockIdx.x * blockDim.x + threadIdx.x) >> 6;
    int lane = threadIdx.x & 63;
    int start = wave * CHUNK;
    if (start >= N) return;
    int end = min(start + CHUNK, N);
    float m = -INFINITY;
    int cur = gid[start];
    for (int n = start; n < end; n++) {
        int g = gid[n];
        if (g != cur) {
            atomicMax(&pooled[cur * 64 + lane], fmap(m));
            cur = g;
            m = -INFINITY;
        }
        m = fmaxf(m, __half2float(x[(size_t)n * 64 + lane]));
    }
    atomicMax(&pooled[cur * 64 + lane], fmap(m));
}

// ---------- FC head + log_softmax, one block (64 threads) per graph ----------
__global__ __launch_bounds__(64) void fc_kernel(
        const unsigned* __restrict__ pooled,
        const float* __restrict__ Wf1, const float* __restrict__ bf1,
        const float* __restrict__ Wf2, const float* __restrict__ bf2,
        const float* __restrict__ Wf3, const float* __restrict__ bf3,
        float* __restrict__ out) {
    int g = blockIdx.x;
    int c = threadIdx.x;
    __shared__ float x0[64], h1[64], h2[32], h3[10];

    unsigned u = pooled[g * 64 + c];
    x0[c] = (u == NEG_INF_MAPPED) ? 0.f : funmap(u);
    __syncthreads();

    float a = bf1[c];
#pragma unroll 8
    for (int k = 0; k < 64; k++) a = fmaf(Wf1[c * 64 + k], x0[k], a);
    h1[c] = elu_f(a);
    __syncthreads();

    if (c < 32) {
        float a2 = bf2[c];
#pragma unroll 8
        for (int k = 0; k < 64; k++) a2 = fmaf(Wf2[c * 64 + k], h1[k], a2);
        h2[c] = elu_f(a2);
    }
    __syncthreads();

    if (c < 10) {
        float a3 = bf3[c];
#pragma unroll 8
        for (int k = 0; k < 32; k++) a3 = fmaf(Wf3[c * 32 + k], h2[k], a3);
        h3[c] = a3;
    }
    __syncthreads();

    if (c < 10) {
        float mx = h3[0];
#pragma unroll
        for (int j = 1; j < 10; j++) mx = fmaxf(mx, h3[j]);
        float s = 0.f;
#pragma unroll
        for (int j = 0; j < 10; j++) s += expf(h3[j] - mx);
        out[g * 10 + c] = h3[c] - mx - logf(s);
    }
}

// ---------- launch ----------
extern "C" void kernel_launch(void* const* d_in, const int* in_sizes, int n_in,
                              void* d_out, int out_size, void* d_ws, size_t ws_size,
                              hipStream_t stream) {
    const float* atom = (const float*)d_in[0];
    const int* esrc = (const int*)d_in[1];
    const int* edst = (const int*)d_in[2];
    const int* gid  = (const int*)d_in[3];
    const float* Wt1 = (const float*)d_in[4];
    const float* bt1 = (const float*)d_in[5];
    const float* Wp1 = (const float*)d_in[6];
    const float* bp1 = (const float*)d_in[7];
    const float* bng = (const float*)d_in[8];
    const float* bnb = (const float*)d_in[9];
    const float* bnm = (const float*)d_in[10];
    const float* bnv = (const float*)d_in[11];
    const float* Wt2 = (const float*)d_in[12];
    const float* bt2 = (const float*)d_in[13];
    const float* Wp2 = (const float*)d_in[14];
    const float* bp2 = (const float*)d_in[15];
    const float* Wt3 = (const float*)d_in[16];
    const float* bt3 = (const float*)d_in[17];
    const float* Wp3 = (const float*)d_in[18];
    const float* bp3 = (const float*)d_in[19];
    const float* Wf1 = (const float*)d_in[20];
    const float* bf1 = (const float*)d_in[21];
    const float* Wf2 = (const float*)d_in[22];
    const float* bf2 = (const float*)d_in[23];
    const float* Wf3 = (const float*)d_in[24];
    const float* bf3 = (const float*)d_in[25];

    // workspace carve-up
    char* p = (char*)d_ws;
    auto alloc = [&](size_t bytes) -> void* {
        void* r = (void*)p;
        p += (bytes + 255) & ~(size_t)255;
        return r;
    };
    int* begs        = (int*)alloc(sizeof(int) * N_NODES);
    int* ends        = (int*)alloc(sizeof(int) * N_NODES);
    int* cursor      = (int*)alloc(sizeof(int) * NB_BUCKETS);
    unsigned* binned = (unsigned*)alloc(sizeof(unsigned) * NB_BUCKETS * BUCKET_PAD);
    int* csr         = (int*)alloc(sizeof(int) * NB_BUCKETS * BUCKET_PAD);
    __half* wsz1 = (__half*)alloc(sizeof(__half) * 128 * 64);
    __half* wsz2 = (__half*)alloc(sizeof(__half) * 32 * 128);
    __half* wsz3 = (__half*)alloc(sizeof(__half) * 64 * 128);
    float* qb1   = (float*)alloc(sizeof(float) * 32);
    float* qb2   = (float*)alloc(sizeof(float) * 64);
    float* qb3   = (float*)alloc(sizeof(float) * 64);
    __half* tbuf = (__half*)alloc(sizeof(__half) * (size_t)N_NODES * 64);
    __half* qbuf = (__half*)alloc(sizeof(__half) * (size_t)N_NODES * 64);
    __half* xh   = (__half*)alloc(sizeof(__half) * (size_t)N_NODES * 64);
    unsigned* pooled = (unsigned*)alloc(sizeof(unsigned) * N_GRAPHS * 64);

    // prep (also zeroes cursor) + CSR build
    prep_kernel<<<32, 256, 0, stream>>>(Wt1, bt1, Wp1, bp1, bng, bnb, bnm, bnv,
                                        Wt2, bt2, Wp2, bp2, Wt3, bt3, Wp3, bp3,
                                        wsz1, qb1, wsz2, qb2, wsz3, qb3, cursor);
    scatter_kernel<<<(N_EDGES + SCAT_CHUNK - 1) / SCAT_CHUNK, 256, 0, stream>>>(
        esrc, edst, cursor, binned, N_EDGES);
    bucket_build_kernel<<<NB_BUCKETS, 256, 0, stream>>>(binned, cursor, begs, ends, csr);

    // layer 1: 128 -> 32 (BN folded), fp32 input
    transform_mfma<128, 32, float><<<1024, 256, 0, stream>>>(atom, wsz1, qb1, tbuf, qbuf);
    edgemax_kernel<32><<<(N_NODES + 63) / 64, 256, 0, stream>>>(
        (const uint4*)tbuf, (const uint4*)qbuf, begs, ends, csr, (uint4*)xh, N_NODES);

    // layer 2: 32 -> 64, fp16 input
    transform_mfma<32, 64, __half><<<1024, 256, 0, stream>>>(xh, wsz2, qb2, tbuf, qbuf);
    edgemax_kernel<64><<<(N_NODES + 31) / 32, 256, 0, stream>>>(
        (const uint4*)tbuf, (const uint4*)qbuf, begs, ends, csr, (uint4*)xh, N_NODES);

    // layer 3: 64 -> 64, fp16 input
    transform_mfma<64, 64, __half><<<1024, 256, 0, stream>>>(xh, wsz3, qb3, tbuf, qbuf);
    edgemax_kernel<64><<<(N_NODES + 31) / 32, 256, 0, stream>>>(
        (const uint4*)tbuf, (const uint4*)qbuf, begs, ends, csr, (uint4*)xh, N_NODES);

    // graph pooling
    pool_init_kernel<<<(N_GRAPHS * 64 + 255) / 256, 256, 0, stream>>>(pooled, N_GRAPHS * 64);
    {
        int waves = (N_NODES + 63) / 64;
        int blocks = (waves + 3) / 4;
        pool_kernel<<<blocks, 256, 0, stream>>>(xh, gid, pooled, N_NODES);
    }

    // FC head
    fc_kernel<<<N_GRAPHS, 64, 0, stream>>>(pooled, Wf1, bf1, Wf2, bf2, Wf3, bf3, (float*)d_out);
}